// Round 4
// baseline (2274.081 us; speedup 1.0000x reference)
//
#include <hip/hip_runtime.h>

// Problem constants (fixed by the reference)
#define NU 100000
#define NV 50000
#define KSUP 5
#define ESUP 400000
#define NEDGE (KSUP * ESUP)   // 2,000,000
#define NE 500000
#define DIN 512
#define DGCN 500
#define FSUP 100     // DGCN / KSUP
#define DSIDE 128
#define HSIDE 64
#define DENC 128
#define NBAS 3
#define NCLS 5

__device__ __forceinline__ ushort f2bf(float x) {
    union { float f; unsigned u; } c; c.f = x;
    unsigned r = (c.u + 0x7FFFu + ((c.u >> 16) & 1u)) >> 16;   // RNE
    return (ushort)r;
}
__device__ __forceinline__ float bf2f(ushort h) {
    union { unsigned u; float f; } c; c.u = ((unsigned)h) << 16;
    return c.f;
}

typedef __attribute__((ext_vector_type(4))) float f32x4;
typedef __attribute__((ext_vector_type(8))) short bf16x8;
typedef __attribute__((address_space(3))) void lds_void;
typedef const __attribute__((address_space(1))) void glob_void;

// ---------------------------------------------------------------------------
// bf16 MFMA GEMM: C[M,N] = A[M,K](bf16,K-major) @ BT[N,K](bf16,K-major)^T
// 128x128 tile, BK=64, 4 waves (2x2). LDS XOR-swizzled via pre-swizzled
// global source (rule #21). STORE_BF16: 1 -> C ushort, 0 -> C float.
template<int STORE_BF16>
__global__ __launch_bounds__(256) void gemm_bf16_k(
    const ushort* __restrict__ A, const ushort* __restrict__ BT,
    void* __restrict__ Cout, int M, int N, int K, int ldc)
{
    __shared__ ushort As[128 * 64];
    __shared__ ushort Bs[128 * 64];
    const int t = threadIdx.x;
    const int lane = t & 63;
    const int w = t >> 6;
    const int wr = w >> 1, wc = w & 1;
    const int rowBase = blockIdx.x * 128;
    const int colBase = blockIdx.y * 128;

    f32x4 acc[4][4] = {};

    for (int k0 = 0; k0 < K; k0 += 64) {
        #pragma unroll
        for (int i = 0; i < 4; ++i) {
            int chi = i * 256 + t;
            int r = chi >> 3;
            int c = (((chi >> 3) & 7) ^ (chi & 7)) * 8;
            int ga = rowBase + r; if (ga > M - 1) ga = M - 1;
            __builtin_amdgcn_global_load_lds(
                (glob_void*)(A + (size_t)ga * K + k0 + c),
                (lds_void*)(As + (size_t)chi * 8), 16, 0, 0);
            int gb = colBase + r; if (gb > N - 1) gb = N - 1;
            __builtin_amdgcn_global_load_lds(
                (glob_void*)(BT + (size_t)gb * K + k0 + c),
                (lds_void*)(Bs + (size_t)chi * 8), 16, 0, 0);
        }
        __syncthreads();

        #pragma unroll
        for (int kk = 0; kk < 2; ++kk) {
            bf16x8 af[4], bfr[4];
            const int cb2 = (kk * 32 + (lane >> 4) * 8) * 2;
            #pragma unroll
            for (int mi = 0; mi < 4; ++mi) {
                int r = wr * 64 + mi * 16 + (lane & 15);
                int off = (r * 128 + cb2) ^ ((r & 7) << 4);
                af[mi] = *(const bf16x8*)((const char*)As + off);
            }
            #pragma unroll
            for (int nj = 0; nj < 4; ++nj) {
                int r = wc * 64 + nj * 16 + (lane & 15);
                int off = (r * 128 + cb2) ^ ((r & 7) << 4);
                bfr[nj] = *(const bf16x8*)((const char*)Bs + off);
            }
            #pragma unroll
            for (int mi = 0; mi < 4; ++mi)
                #pragma unroll
                for (int nj = 0; nj < 4; ++nj)
                    acc[mi][nj] = __builtin_amdgcn_mfma_f32_16x16x32_bf16(
                        af[mi], bfr[nj], acc[mi][nj], 0, 0, 0);
        }
        __syncthreads();
    }

    #pragma unroll
    for (int mi = 0; mi < 4; ++mi) {
        #pragma unroll
        for (int q = 0; q < 4; ++q) {
            int gr = rowBase + wr * 64 + mi * 16 + (lane >> 4) * 4 + q;
            if (gr >= M) continue;
            #pragma unroll
            for (int nj = 0; nj < 4; ++nj) {
                int gc = colBase + wc * 64 + nj * 16 + (lane & 15);
                float v = acc[mi][nj][q];
                if (STORE_BF16)
                    ((ushort*)Cout)[(size_t)gr * ldc + gc] = f2bf(v);
                else
                    ((float*)Cout)[(size_t)gr * ldc + gc] = v;
            }
        }
    }
}

// ---------------------------------------------------------------------------
// fp32 tiled GEMM (side dense only): C = relu(A@B + bias)
#define BM 64
#define BN 64
#define BK 16
__global__ __launch_bounds__(256) void gemm_side_k(
    const float* __restrict__ A, const float* __restrict__ B,
    const float* __restrict__ bias, float* __restrict__ C,
    int M, int N, int K)
{
    __shared__ float As[BK][BM + 4];
    __shared__ float Bs[BK][BN + 4];
    const int t = threadIdx.x;
    const int rowBase = blockIdx.x * BM;
    const int ty = t >> 4, tx = t & 15;
    float acc[4][4] = {};

    for (int k0 = 0; k0 < K; k0 += BK) {
        #pragma unroll
        for (int p = 0; p < 4; ++p) {
            int r = p * 16 + (t >> 4), kk = t & 15;
            int gr = rowBase + r, gk = k0 + kk;
            As[kk][r] = (gr < M && gk < K) ? A[(size_t)gr * K + gk] : 0.f;
        }
        #pragma unroll
        for (int p = 0; p < 4; ++p) {
            int kk = p * 4 + (t >> 6), j = t & 63;
            int gk = k0 + kk;
            Bs[kk][j] = (j < N && gk < K) ? B[(size_t)gk * N + j] : 0.f;
        }
        __syncthreads();
        #pragma unroll
        for (int kk = 0; kk < BK; ++kk) {
            float4 a4 = *reinterpret_cast<const float4*>(&As[kk][ty * 4]);
            float4 b4 = *reinterpret_cast<const float4*>(&Bs[kk][tx * 4]);
            float aa[4] = {a4.x, a4.y, a4.z, a4.w};
            float bb[4] = {b4.x, b4.y, b4.z, b4.w};
            #pragma unroll
            for (int i = 0; i < 4; ++i)
                #pragma unroll
                for (int j = 0; j < 4; ++j)
                    acc[i][j] = fmaf(aa[i], bb[j], acc[i][j]);
        }
        __syncthreads();
    }
    #pragma unroll
    for (int i = 0; i < 4; ++i) {
        int gr = rowBase + ty * 4 + i;
        if (gr >= M) continue;
        #pragma unroll
        for (int j = 0; j < 4; ++j) {
            int gc = tx * 4 + j;
            if (gc < N) C[(size_t)gr * N + gc] = fmaxf(acc[i][j] + bias[gc], 0.f);
        }
    }
}

// ---------------------------------------------------------------------------
// conversions
__global__ __launch_bounds__(256) void cvt_k(const float* __restrict__ in,
                                             ushort* __restrict__ out, long n) {
    long i = ((long)blockIdx.x * 256 + threadIdx.x) * 4;
    if (i >= n) return;
    float4 v = *(const float4*)(in + i);
    ushort4 o;
    o.x = f2bf(v.x); o.y = f2bf(v.y); o.z = f2bf(v.z); o.w = f2bf(v.w);
    *(ushort4*)(out + i) = o;
}

__global__ __launch_bounds__(256) void cvt_wencT_k(const float* __restrict__ W,
                                                   ushort* __restrict__ out) {
    int idx = blockIdx.x * 256 + threadIdx.x;
    int c = idx >> 9, d = idx & 511;
    float v = 0.f;
    if (c < DGCN) {
        int s = c / FSUP, f = c - s * FSUP;
        v = W[((size_t)s * DIN + d) * FSUP + f];
    }
    out[idx] = f2bf(v);
}

__global__ __launch_bounds__(256) void cvt_w2aT_k(const float* __restrict__ W2,
                                                  ushort* __restrict__ out) {
    int idx = blockIdx.x * 256 + threadIdx.x;
    int j = idx >> 9, c = idx & 511;
    float v = (c < DGCN) ? W2[(size_t)c * DENC + j] : 0.f;
    out[idx] = f2bf(v);
}

__global__ __launch_bounds__(256) void cvt_decWT_k(const float* __restrict__ W,
                                                   ushort* __restrict__ out) {
    int idx = blockIdx.x * 256 + threadIdx.x;       // 384*128
    int p = idx >> 7, k = idx & 127;
    int b = p >> 7, j = p & 127;
    out[idx] = f2bf(W[((size_t)b * DENC + k) * DENC + j]);
}

// emb[n][j] (+= side part); OUT_BF16 selects bf16 vs f32 destination
template<int OUT_BF16>
__global__ __launch_bounds__(256) void accum_side_k(const float* __restrict__ side,
                                                    const float* __restrict__ W2,
                                                    const float* __restrict__ embIn,
                                                    void* __restrict__ embOut, int M) {
    __shared__ float Ws[HSIDE][DENC];
    for (int i = threadIdx.x; i < HSIDE * DENC; i += 256)
        Ws[i >> 7][i & 127] = W2[(size_t)(DGCN + (i >> 7)) * DENC + (i & 127)];
    __syncthreads();
    int n = blockIdx.x * 2 + (threadIdx.x >> 7);
    if (n >= M) return;
    int j = threadIdx.x & 127;
    const float* s = side + (size_t)n * HSIDE;
    float a = embIn[(size_t)n * DENC + j];
    #pragma unroll 8
    for (int h = 0; h < HSIDE; ++h) a = fmaf(s[h], Ws[h][j], a);
    if (OUT_BF16) ((ushort*)embOut)[(size_t)n * DENC + j] = f2bf(a);
    else          ((float*)embOut)[(size_t)n * DENC + j] = a;
}

// ---------------------------------------------------------------------------
// CSR build: histogram, 3-kernel exclusive scan, scatter (packed int2)
__global__ __launch_bounds__(256) void hist_k(
    const int* __restrict__ su, const int* __restrict__ si,
    int* __restrict__ histU, int* __restrict__ histV)
{
    int e = blockIdx.x * 256 + threadIdx.x;
    if (e >= NEDGE) return;
    int k = e / ESUP;
    atomicAdd(&histU[k * NU + su[e]], 1);
    atomicAdd(&histV[k * NV + si[e]], 1);
}

__global__ __launch_bounds__(256) void scan_reduce_k(const int* __restrict__ in,
                                                     int* __restrict__ bs, int n) {
    __shared__ int sm[256];
    int base = blockIdx.x * 2048 + threadIdx.x * 8;
    int s = 0;
    #pragma unroll
    for (int i = 0; i < 8; ++i) { int idx = base + i; if (idx < n) s += in[idx]; }
    sm[threadIdx.x] = s; __syncthreads();
    for (int off = 128; off; off >>= 1) {
        if (threadIdx.x < off) sm[threadIdx.x] += sm[threadIdx.x + off];
        __syncthreads();
    }
    if (threadIdx.x == 0) bs[blockIdx.x] = sm[0];
}

// single block: exclusive scan of bs[0..nb), nb <= 256
__global__ __launch_bounds__(256) void scan_bs_k(int* __restrict__ bs, int nb) {
    __shared__ int sm[256];
    int t = threadIdx.x;
    int v = (t < nb) ? bs[t] : 0;
    sm[t] = v; __syncthreads();
    for (int off = 1; off < 256; off <<= 1) {
        int add = (t >= off) ? sm[t - off] : 0;
        __syncthreads();
        sm[t] += add;
        __syncthreads();
    }
    if (t < nb) bs[t] = sm[t] - v;   // exclusive
}

__global__ __launch_bounds__(256) void scan_write_k(const int* __restrict__ in,
                                                    const int* __restrict__ bs,
                                                    int* __restrict__ out, int n) {
    __shared__ int sm[256];
    int t = threadIdx.x;
    int base = blockIdx.x * 2048 + t * 8;
    int loc[8]; int s = 0;
    #pragma unroll
    for (int i = 0; i < 8; ++i) {
        int idx = base + i;
        loc[i] = (idx < n) ? in[idx] : 0;
        s += loc[i];
    }
    sm[t] = s; __syncthreads();
    int sv = s;
    for (int off = 1; off < 256; off <<= 1) {
        int add = (t >= off) ? sm[t - off] : 0;
        __syncthreads();
        sm[t] += add;
        __syncthreads();
    }
    int thOff = bs[blockIdx.x] + sm[t] - sv;
    int run = 0;
    #pragma unroll
    for (int i = 0; i < 8; ++i) {
        int idx = base + i;
        if (idx < n) out[idx] = thOff + run;
        run += loc[i];
    }
}

// packed scatter: one 8B (idx, valbits) write per direction per edge
__global__ __launch_bounds__(256) void scatter_k(
    const int* __restrict__ su, const int* __restrict__ si,
    const float* __restrict__ sv,
    int* __restrict__ posU, int* __restrict__ posV,
    int2* __restrict__ eU, int2* __restrict__ eV)
{
    int e = blockIdx.x * 256 + threadIdx.x;
    if (e >= NEDGE) return;
    int k = e / ESUP;
    int r = su[e], c = si[e];
    int vb = __float_as_int(sv[e]);
    int pu = atomicAdd(&posU[k * NU + r], 1);
    eU[pu] = make_int2(c, vb);
    int pv = atomicAdd(&posV[k * NV + c], 1);
    eV[pv] = make_int2(r, vb);
}

// ---------------------------------------------------------------------------
// CSR aggregation, all supports (blockIdx.y = k), both directions.
// 128 threads/node, register accumulation, one coalesced bf16 write into
// packed X[n][512] (col slice [k*100,(k+1)*100)); k==4 zeroes pad cols.
__global__ __launch_bounds__(256) void agg_csr_k(
    const int* __restrict__ rowPtrU, const int2* __restrict__ eU,
    const int* __restrict__ rowPtrV, const int2* __restrict__ eV,
    const ushort* __restrict__ tmpU, const ushort* __restrict__ tmpV,
    ushort* __restrict__ Xu, ushort* __restrict__ Xv)
{
    int k = blockIdx.y;
    int half = blockIdx.x;
    int j = threadIdx.x & 127;
    int sub = threadIdx.x >> 7;
    if (half < NU / 2) {
        int n = half * 2 + sub;
        int g = k * NU + n;
        int s = rowPtrU[g];
        int e = (g == KSUP * NU - 1) ? NEDGE : rowPtrU[g + 1];
        float acc = 0.f;
        for (int p = s; p < e; ++p) {
            int2 ed = eU[p];
            float v = __int_as_float(ed.y);
            if (j < FSUP) acc += v * bf2f(tmpV[(size_t)ed.x * 512 + k * FSUP + j]);
        }
        if (j < FSUP) Xu[(size_t)n * 512 + k * FSUP + j] = f2bf(fmaxf(acc, 0.f));
        else if (k == 4 && j < 112) Xu[(size_t)n * 512 + 400 + j] = 0;
    } else {
        int n = (half - NU / 2) * 2 + sub;
        int g = k * NV + n;
        int s = rowPtrV[g];
        int e = (g == KSUP * NV - 1) ? NEDGE : rowPtrV[g + 1];
        float acc = 0.f;
        for (int p = s; p < e; ++p) {
            int2 ed = eV[p];
            float v = __int_as_float(ed.y);
            if (j < FSUP) acc += v * bf2f(tmpU[(size_t)ed.x * 512 + k * FSUP + j]);
        }
        if (j < FSUP) Xv[(size_t)n * 512 + k * FSUP + j] = f2bf(fmaxf(acc, 0.f));
        else if (k == 4 && j < 112) Xv[(size_t)n * 512 + 400 + j] = 0;
    }
}

// ---------------------------------------------------------------------------
// final decoder: basis[b] = dot(bf16 Ub[u][b*128..], bf16 embV[v]); out = basis@cls
__global__ __launch_bounds__(256) void dec_k(
    const int* __restrict__ ue, const int* __restrict__ ie,
    const ushort* __restrict__ Ub, const ushort* __restrict__ embV,
    const float* __restrict__ cls, float* __restrict__ out, int nE)
{
    int e = blockIdx.x * 8 + (threadIdx.x >> 5);
    if (e >= nE) return;
    int lane = threadIdx.x & 31;
    int u = ue[e], v = ie[e];
    const ushort* pv = embV + (size_t)v * DENC;
    float vb[4];
    #pragma unroll
    for (int i = 0; i < 4; ++i) vb[i] = bf2f(pv[lane + i * 32]);
    float basis[NBAS];
    #pragma unroll
    for (int b = 0; b < NBAS; ++b) {
        const ushort* pu = Ub + (size_t)u * (NBAS * DENC) + b * DENC;
        float s = 0.f;
        #pragma unroll
        for (int i = 0; i < 4; ++i) s += bf2f(pu[lane + i * 32]) * vb[i];
        #pragma unroll
        for (int off = 16; off; off >>= 1) s += __shfl_xor(s, off, 32);
        basis[b] = s;
    }
    if (lane < NCLS) {
        float o = 0.f;
        #pragma unroll
        for (int b = 0; b < NBAS; ++b) o += basis[b] * cls[b * NCLS + lane];
        out[(size_t)e * NCLS + lane] = o;
    }
}

// ---------------------------------------------------------------------------
extern "C" void kernel_launch(void* const* d_in, const int* in_sizes, int n_in,
                              void* d_out, int out_size, void* d_ws, size_t ws_size,
                              hipStream_t stream) {
    const int*   sup_u  = (const int*)  d_in[0];
    const int*   sup_i  = (const int*)  d_in[1];
    const float* sup_v  = (const float*)d_in[2];
    const float* u_in   = (const float*)d_in[3];
    const float* v_in   = (const float*)d_in[4];
    const float* u_side = (const float*)d_in[5];
    const float* v_side = (const float*)d_in[6];
    const int*   ue     = (const int*)  d_in[7];
    const int*   ie     = (const int*)  d_in[8];
    const float* W_enc  = (const float*)d_in[9];
    const float* Wu1    = (const float*)d_in[10];
    const float* bu1    = (const float*)d_in[11];
    const float* Wi1    = (const float*)d_in[12];
    const float* bi1    = (const float*)d_in[13];
    const float* Wu2    = (const float*)d_in[14];
    const float* Wi2    = (const float*)d_in[15];
    const float* dec_W  = (const float*)d_in[16];
    const float* deccls = (const float*)d_in[17];

    char* ws = (char*)d_ws;
    // Region @0 (timeline-overlaid):
    //   ph1-2: u_bf [NU][512] bf16 @0 (102.4M), v_bf [NV][512] @102.4M (51.2M)
    //   ph3+ : Xu @0, Xv @102.4M (written by agg after u_bf dead)
    //   ph6  : embUbf @0 (25.6M, after dense2 U done), Ub bf16 @26M (76.8M)
    ushort* u_bf   = (ushort*)(ws);
    ushort* v_bf   = (ushort*)(ws + 102400000LL);
    ushort* Xu     = (ushort*)(ws);
    ushort* Xv     = (ushort*)(ws + 102400000LL);
    ushort* embUbf = (ushort*)(ws);
    ushort* Ub     = (ushort*)(ws + 26000000LL);
    // CSR region @156M (dead after agg):
    int*    histU  = (int*)(ws + 156000000LL);          // [5][NU]
    int*    histV  = (int*)(ws + 158000000LL);          // [5][NV]
    int*    rowPtrU= (int*)(ws + 159000000LL);          // [5][NU]
    int*    rowPtrV= (int*)(ws + 161000000LL);          // [5][NV]
    int*    posU   = (int*)(ws + 162000000LL);          // [5][NU]
    int*    posV   = (int*)(ws + 164000000LL);          // [5][NV]
    int*    bsums  = (int*)(ws + 165000000LL);          // 1024
    int2*   eU     = (int2*)(ws + 165010000LL);         // [2M] packed (idx,val)
    int2*   eV     = (int2*)(ws + 181010000LL);         // [2M] ends 197.01M
    // Post-agg region (over dead CSR):
    float*  sideU  = (float*)(ws + 200000000LL);        // [NU][64]
    float*  sideV  = (float*)(ws + 226000000LL);        // [NV][64]
    float*  embU   = (float*)(ws + 240000000LL);        // [NU][128] f32
    // tmp region @300M (live ph2..agg; embV/embVbf overlay after)
    ushort* tmpU   = (ushort*)(ws + 300000000LL);       // [NU][512] bf16
    ushort* tmpV   = (ushort*)(ws + 402400000LL);       // [NV][512] bf16
    float*  embV   = (float*)(ws + 300000000LL);        // [NV][128] f32 (ends 325.6M)
    ushort* embVbf = (ushort*)(ws + 326000000LL);       // [NV][128] bf16 (12.8M)
    // weights @453.6M:
    ushort* WencT  = (ushort*)(ws + 453600000LL);       // [512][512]
    ushort* W2uaT  = (ushort*)(ws + 454124288LL);       // [128][512]
    ushort* W2iaT  = (ushort*)(ws + 454255360LL);       // [128][512]
    ushort* decWT  = (ushort*)(ws + 454386432LL);       // [384][128]

    dim3 blk(256);
    const int gu128 = (NU + 127) / 128;   // 782
    const int gv128 = (NV + 127) / 128;   // 391
    const int gu64  = (NU + 63) / 64;     // 1563
    const int gv64  = (NV + 63) / 64;     // 782
    const int gE    = (NEDGE + 255) / 256;

    // ---- phase 1: bf16 conversions + CSR build ----
    cvt_k<<<dim3((NU * 512 / 4 + 255) / 256), blk, 0, stream>>>(u_in, u_bf, (long)NU * 512);
    cvt_k<<<dim3((NV * 512 / 4 + 255) / 256), blk, 0, stream>>>(v_in, v_bf, (long)NV * 512);
    cvt_wencT_k<<<dim3(512 * 512 / 256), blk, 0, stream>>>(W_enc, WencT);
    cvt_w2aT_k<<<dim3(128 * 512 / 256), blk, 0, stream>>>(Wu2, W2uaT);
    cvt_w2aT_k<<<dim3(128 * 512 / 256), blk, 0, stream>>>(Wi2, W2iaT);
    cvt_decWT_k<<<dim3(384 * 128 / 256), blk, 0, stream>>>(dec_W, decWT);

    hipMemsetAsync(histU, 0, 3000000LL, stream);   // histU + histV contiguous
    hist_k<<<dim3(gE), blk, 0, stream>>>(sup_u, sup_i, histU, histV);
    scan_reduce_k<<<dim3(245), blk, 0, stream>>>(histU, bsums, KSUP * NU);
    scan_bs_k<<<dim3(1), blk, 0, stream>>>(bsums, 245);
    scan_write_k<<<dim3(245), blk, 0, stream>>>(histU, bsums, rowPtrU, KSUP * NU);
    scan_reduce_k<<<dim3(123), blk, 0, stream>>>(histV, bsums, KSUP * NV);
    scan_bs_k<<<dim3(1), blk, 0, stream>>>(bsums, 123);
    scan_write_k<<<dim3(123), blk, 0, stream>>>(histV, bsums, rowPtrV, KSUP * NV);
    hipMemcpyAsync(posU, rowPtrU, (size_t)KSUP * NU * 4, hipMemcpyDeviceToDevice, stream);
    hipMemcpyAsync(posV, rowPtrV, (size_t)KSUP * NV * 4, hipMemcpyDeviceToDevice, stream);
    scatter_k<<<dim3(gE), blk, 0, stream>>>(sup_u, sup_i, sup_v, posU, posV, eU, eV);

    // ---- phase 2: fused encoder GEMMs (bf16 out) ----
    gemm_bf16_k<1><<<dim3(gu128, 4), blk, 0, stream>>>(u_bf, WencT, tmpU, NU, 512, 512, 512);
    gemm_bf16_k<1><<<dim3(gv128, 4), blk, 0, stream>>>(v_bf, WencT, tmpV, NV, 512, 512, 512);

    // ---- phase 3: CSR aggregation (all supports), writes packed relu'd X ----
    agg_csr_k<<<dim3(NU / 2 + NV / 2, KSUP), blk, 0, stream>>>(
        rowPtrU, eU, rowPtrV, eV, tmpU, tmpV, Xu, Xv);

    // ---- phase 4: side dense (fp32) ----
    gemm_side_k<<<dim3(gu64), blk, 0, stream>>>(u_side, Wu1, bu1, sideU, NU, HSIDE, DSIDE);
    gemm_side_k<<<dim3(gv64), blk, 0, stream>>>(v_side, Wi1, bi1, sideV, NV, HSIDE, DSIDE);

    // ---- phase 5: dense2 = X @ W2aT (MFMA) + side part (emits bf16) ----
    gemm_bf16_k<0><<<dim3(gu128, 1), blk, 0, stream>>>(Xu, W2uaT, embU, NU, 128, 512, 128);
    gemm_bf16_k<0><<<dim3(gv128, 1), blk, 0, stream>>>(Xv, W2iaT, embV, NV, 128, 512, 128);
    accum_side_k<1><<<dim3((NV + 1) / 2), blk, 0, stream>>>(sideV, Wi2, embV, embVbf, NV);
    accum_side_k<1><<<dim3((NU + 1) / 2), blk, 0, stream>>>(sideU, Wu2, embU, embUbf, NU);

    // ---- phase 6: decoder precompute Ub (bf16 out) ----
    gemm_bf16_k<1><<<dim3(gu128, 3), blk, 0, stream>>>(embUbf, decWT, Ub, NU, 384, 128, 384);

    // ---- phase 7: final decoder over edges ----
    dec_k<<<dim3(NE / 8), blk, 0, stream>>>(ue, ie, Ub, embVbf, deccls, (float*)d_out, NE);
}

// Round 5
// 1919.103 us; speedup vs baseline: 1.1850x; 1.1850x over previous
//
#include <hip/hip_runtime.h>

// Problem constants (fixed by the reference)
#define NU 100000
#define NV 50000
#define KSUP 5
#define ESUP 400000
#define NEDGE (KSUP * ESUP)   // 2,000,000
#define NE 500000
#define DIN 512
#define DGCN 500
#define FSUP 100     // DGCN / KSUP
#define DSIDE 128
#define HSIDE 64
#define DENC 128
#define NBAS 3
#define NCLS 5

__device__ __forceinline__ ushort f2bf(float x) {
    union { float f; unsigned u; } c; c.f = x;
    unsigned r = (c.u + 0x7FFFu + ((c.u >> 16) & 1u)) >> 16;   // RNE
    return (ushort)r;
}
__device__ __forceinline__ float bf2f(ushort h) {
    union { unsigned u; float f; } c; c.u = ((unsigned)h) << 16;
    return c.f;
}

typedef __attribute__((ext_vector_type(4))) float f32x4;
typedef __attribute__((ext_vector_type(8))) short bf16x8;
typedef __attribute__((address_space(3))) void lds_void;
typedef const __attribute__((address_space(1))) void glob_void;

// ---------------------------------------------------------------------------
// bf16 MFMA GEMM: C[M,N] = A[M,K](bf16,K-major) @ BT[N,K](bf16,K-major)^T
// 128x128 tile, BK=64, 4 waves (2x2). LDS XOR-swizzled via pre-swizzled
// global source (rule #21). STORE_BF16: 1 -> C ushort, 0 -> C float.
template<int STORE_BF16>
__global__ __launch_bounds__(256) void gemm_bf16_k(
    const ushort* __restrict__ A, const ushort* __restrict__ BT,
    void* __restrict__ Cout, int M, int N, int K, int ldc)
{
    __shared__ ushort As[128 * 64];
    __shared__ ushort Bs[128 * 64];
    const int t = threadIdx.x;
    const int lane = t & 63;
    const int w = t >> 6;
    const int wr = w >> 1, wc = w & 1;
    const int rowBase = blockIdx.x * 128;
    const int colBase = blockIdx.y * 128;

    f32x4 acc[4][4] = {};

    for (int k0 = 0; k0 < K; k0 += 64) {
        #pragma unroll
        for (int i = 0; i < 4; ++i) {
            int chi = i * 256 + t;
            int r = chi >> 3;
            int c = (((chi >> 3) & 7) ^ (chi & 7)) * 8;
            int ga = rowBase + r; if (ga > M - 1) ga = M - 1;
            __builtin_amdgcn_global_load_lds(
                (glob_void*)(A + (size_t)ga * K + k0 + c),
                (lds_void*)(As + (size_t)chi * 8), 16, 0, 0);
            int gb = colBase + r; if (gb > N - 1) gb = N - 1;
            __builtin_amdgcn_global_load_lds(
                (glob_void*)(BT + (size_t)gb * K + k0 + c),
                (lds_void*)(Bs + (size_t)chi * 8), 16, 0, 0);
        }
        __syncthreads();

        #pragma unroll
        for (int kk = 0; kk < 2; ++kk) {
            bf16x8 af[4], bfr[4];
            const int cb2 = (kk * 32 + (lane >> 4) * 8) * 2;
            #pragma unroll
            for (int mi = 0; mi < 4; ++mi) {
                int r = wr * 64 + mi * 16 + (lane & 15);
                int off = (r * 128 + cb2) ^ ((r & 7) << 4);
                af[mi] = *(const bf16x8*)((const char*)As + off);
            }
            #pragma unroll
            for (int nj = 0; nj < 4; ++nj) {
                int r = wc * 64 + nj * 16 + (lane & 15);
                int off = (r * 128 + cb2) ^ ((r & 7) << 4);
                bfr[nj] = *(const bf16x8*)((const char*)Bs + off);
            }
            #pragma unroll
            for (int mi = 0; mi < 4; ++mi)
                #pragma unroll
                for (int nj = 0; nj < 4; ++nj)
                    acc[mi][nj] = __builtin_amdgcn_mfma_f32_16x16x32_bf16(
                        af[mi], bfr[nj], acc[mi][nj], 0, 0, 0);
        }
        __syncthreads();
    }

    #pragma unroll
    for (int mi = 0; mi < 4; ++mi) {
        #pragma unroll
        for (int q = 0; q < 4; ++q) {
            int gr = rowBase + wr * 64 + mi * 16 + (lane >> 4) * 4 + q;
            if (gr >= M) continue;
            #pragma unroll
            for (int nj = 0; nj < 4; ++nj) {
                int gc = colBase + wc * 64 + nj * 16 + (lane & 15);
                float v = acc[mi][nj][q];
                if (STORE_BF16)
                    ((ushort*)Cout)[(size_t)gr * ldc + gc] = f2bf(v);
                else
                    ((float*)Cout)[(size_t)gr * ldc + gc] = v;
            }
        }
    }
}

// ---------------------------------------------------------------------------
// fp32 tiled GEMM (side dense only): C = relu(A@B + bias)
#define BM 64
#define BN 64
#define BK 16
__global__ __launch_bounds__(256) void gemm_side_k(
    const float* __restrict__ A, const float* __restrict__ B,
    const float* __restrict__ bias, float* __restrict__ C,
    int M, int N, int K)
{
    __shared__ float As[BK][BM + 4];
    __shared__ float Bs[BK][BN + 4];
    const int t = threadIdx.x;
    const int rowBase = blockIdx.x * BM;
    const int ty = t >> 4, tx = t & 15;
    float acc[4][4] = {};

    for (int k0 = 0; k0 < K; k0 += BK) {
        #pragma unroll
        for (int p = 0; p < 4; ++p) {
            int r = p * 16 + (t >> 4), kk = t & 15;
            int gr = rowBase + r, gk = k0 + kk;
            As[kk][r] = (gr < M && gk < K) ? A[(size_t)gr * K + gk] : 0.f;
        }
        #pragma unroll
        for (int p = 0; p < 4; ++p) {
            int kk = p * 4 + (t >> 6), j = t & 63;
            int gk = k0 + kk;
            Bs[kk][j] = (j < N && gk < K) ? B[(size_t)gk * N + j] : 0.f;
        }
        __syncthreads();
        #pragma unroll
        for (int kk = 0; kk < BK; ++kk) {
            float4 a4 = *reinterpret_cast<const float4*>(&As[kk][ty * 4]);
            float4 b4 = *reinterpret_cast<const float4*>(&Bs[kk][tx * 4]);
            float aa[4] = {a4.x, a4.y, a4.z, a4.w};
            float bb[4] = {b4.x, b4.y, b4.z, b4.w};
            #pragma unroll
            for (int i = 0; i < 4; ++i)
                #pragma unroll
                for (int j = 0; j < 4; ++j)
                    acc[i][j] = fmaf(aa[i], bb[j], acc[i][j]);
        }
        __syncthreads();
    }
    #pragma unroll
    for (int i = 0; i < 4; ++i) {
        int gr = rowBase + ty * 4 + i;
        if (gr >= M) continue;
        #pragma unroll
        for (int j = 0; j < 4; ++j) {
            int gc = tx * 4 + j;
            if (gc < N) C[(size_t)gr * N + gc] = fmaxf(acc[i][j] + bias[gc], 0.f);
        }
    }
}

// ---------------------------------------------------------------------------
// conversions
__global__ __launch_bounds__(256) void cvt_k(const float* __restrict__ in,
                                             ushort* __restrict__ out, long n) {
    long i = ((long)blockIdx.x * 256 + threadIdx.x) * 4;
    if (i >= n) return;
    float4 v = *(const float4*)(in + i);
    ushort4 o;
    o.x = f2bf(v.x); o.y = f2bf(v.y); o.z = f2bf(v.z); o.w = f2bf(v.w);
    *(ushort4*)(out + i) = o;
}

__global__ __launch_bounds__(256) void cvt_wencT_k(const float* __restrict__ W,
                                                   ushort* __restrict__ out) {
    int idx = blockIdx.x * 256 + threadIdx.x;
    int c = idx >> 9, d = idx & 511;
    float v = 0.f;
    if (c < DGCN) {
        int s = c / FSUP, f = c - s * FSUP;
        v = W[((size_t)s * DIN + d) * FSUP + f];
    }
    out[idx] = f2bf(v);
}

__global__ __launch_bounds__(256) void cvt_w2aT_k(const float* __restrict__ W2,
                                                  ushort* __restrict__ out) {
    int idx = blockIdx.x * 256 + threadIdx.x;
    int j = idx >> 9, c = idx & 511;
    float v = (c < DGCN) ? W2[(size_t)c * DENC + j] : 0.f;
    out[idx] = f2bf(v);
}

__global__ __launch_bounds__(256) void cvt_decWT_k(const float* __restrict__ W,
                                                   ushort* __restrict__ out) {
    int idx = blockIdx.x * 256 + threadIdx.x;       // 384*128
    int p = idx >> 7, k = idx & 127;
    int b = p >> 7, j = p & 127;
    out[idx] = f2bf(W[((size_t)b * DENC + k) * DENC + j]);
}

// emb[n][j] (+= side part); OUT_BF16 selects bf16 vs f32 destination
template<int OUT_BF16>
__global__ __launch_bounds__(256) void accum_side_k(const float* __restrict__ side,
                                                    const float* __restrict__ W2,
                                                    const float* __restrict__ embIn,
                                                    void* __restrict__ embOut, int M) {
    __shared__ float Ws[HSIDE][DENC];
    for (int i = threadIdx.x; i < HSIDE * DENC; i += 256)
        Ws[i >> 7][i & 127] = W2[(size_t)(DGCN + (i >> 7)) * DENC + (i & 127)];
    __syncthreads();
    int n = blockIdx.x * 2 + (threadIdx.x >> 7);
    if (n >= M) return;
    int j = threadIdx.x & 127;
    const float* s = side + (size_t)n * HSIDE;
    float a = embIn[(size_t)n * DENC + j];
    #pragma unroll 8
    for (int h = 0; h < HSIDE; ++h) a = fmaf(s[h], Ws[h][j], a);
    if (OUT_BF16) ((ushort*)embOut)[(size_t)n * DENC + j] = f2bf(a);
    else          ((float*)embOut)[(size_t)n * DENC + j] = a;
}

// ---------------------------------------------------------------------------
// CSR build: histogram, 3-kernel exclusive scan, scatter (packed int2)
__global__ __launch_bounds__(256) void hist_k(
    const int* __restrict__ su, const int* __restrict__ si,
    int* __restrict__ histU, int* __restrict__ histV)
{
    int e = blockIdx.x * 256 + threadIdx.x;
    if (e >= NEDGE) return;
    int k = e / ESUP;
    atomicAdd(&histU[k * NU + su[e]], 1);
    atomicAdd(&histV[k * NV + si[e]], 1);
}

__global__ __launch_bounds__(256) void scan_reduce_k(const int* __restrict__ in,
                                                     int* __restrict__ bs, int n) {
    __shared__ int sm[256];
    int base = blockIdx.x * 2048 + threadIdx.x * 8;
    int s = 0;
    #pragma unroll
    for (int i = 0; i < 8; ++i) { int idx = base + i; if (idx < n) s += in[idx]; }
    sm[threadIdx.x] = s; __syncthreads();
    for (int off = 128; off; off >>= 1) {
        if (threadIdx.x < off) sm[threadIdx.x] += sm[threadIdx.x + off];
        __syncthreads();
    }
    if (threadIdx.x == 0) bs[blockIdx.x] = sm[0];
}

// single block: exclusive scan of bs[0..nb), nb <= 256
__global__ __launch_bounds__(256) void scan_bs_k(int* __restrict__ bs, int nb) {
    __shared__ int sm[256];
    int t = threadIdx.x;
    int v = (t < nb) ? bs[t] : 0;
    sm[t] = v; __syncthreads();
    for (int off = 1; off < 256; off <<= 1) {
        int add = (t >= off) ? sm[t - off] : 0;
        __syncthreads();
        sm[t] += add;
        __syncthreads();
    }
    if (t < nb) bs[t] = sm[t] - v;   // exclusive
}

__global__ __launch_bounds__(256) void scan_write_k(const int* __restrict__ in,
                                                    const int* __restrict__ bs,
                                                    int* __restrict__ out, int n) {
    __shared__ int sm[256];
    int t = threadIdx.x;
    int base = blockIdx.x * 2048 + t * 8;
    int loc[8]; int s = 0;
    #pragma unroll
    for (int i = 0; i < 8; ++i) {
        int idx = base + i;
        loc[i] = (idx < n) ? in[idx] : 0;
        s += loc[i];
    }
    sm[t] = s; __syncthreads();
    int sv = s;
    for (int off = 1; off < 256; off <<= 1) {
        int add = (t >= off) ? sm[t - off] : 0;
        __syncthreads();
        sm[t] += add;
        __syncthreads();
    }
    int thOff = bs[blockIdx.x] + sm[t] - sv;
    int run = 0;
    #pragma unroll
    for (int i = 0; i < 8; ++i) {
        int idx = base + i;
        if (idx < n) out[idx] = thOff + run;
        run += loc[i];
    }
}

// packed scatter: one 8B (idx, valbits) write per direction per edge
__global__ __launch_bounds__(256) void scatter_k(
    const int* __restrict__ su, const int* __restrict__ si,
    const float* __restrict__ sv,
    int* __restrict__ posU, int* __restrict__ posV,
    int2* __restrict__ eU, int2* __restrict__ eV)
{
    int e = blockIdx.x * 256 + threadIdx.x;
    if (e >= NEDGE) return;
    int k = e / ESUP;
    int r = su[e], c = si[e];
    int vb = __float_as_int(sv[e]);
    int pu = atomicAdd(&posU[k * NU + r], 1);
    eU[pu] = make_int2(c, vb);
    int pv = atomicAdd(&posV[k * NV + c], 1);
    eV[pv] = make_int2(r, vb);
}

// ---------------------------------------------------------------------------
// CSR aggregation, all supports (blockIdx.y = k), both directions.
// 128 threads/node. Batched MLP inner loop: load B edges (clamped, branch-
// free), issue all B gathers, then accumulate. NT stores keep L2/L3 for tmp.
__global__ __launch_bounds__(256) void agg_csr_k(
    const int* __restrict__ rowPtrU, const int2* __restrict__ eU,
    const int* __restrict__ rowPtrV, const int2* __restrict__ eV,
    const ushort* __restrict__ tmpU, const ushort* __restrict__ tmpV,
    ushort* __restrict__ Xu, ushort* __restrict__ Xv)
{
    const int k = blockIdx.y;
    const int half = blockIdx.x;
    const int j = threadIdx.x & 127;
    const int sub = threadIdx.x >> 7;
    const int jj = (j < FSUP) ? j : (FSUP - 1);
    const int colOff = k * FSUP;

    if (half < NU / 2) {
        // U direction: avg degree 4, batch 4
        const int n = half * 2 + sub;
        const int g = k * NU + n;
        const int s = rowPtrU[g];
        const int e = (g == KSUP * NU - 1) ? NEDGE : rowPtrU[g + 1];
        const int d = e - s;
        float acc = 0.f;
        for (int base = 0; base < d; base += 4) {
            int2 ed[4];
            #pragma unroll
            for (int i = 0; i < 4; ++i) {
                int idx = base + i; if (idx >= d) idx = base;
                ed[i] = eU[s + idx];
            }
            float tv[4];
            #pragma unroll
            for (int i = 0; i < 4; ++i)
                tv[i] = bf2f(tmpV[(size_t)ed[i].x * 512 + colOff + jj]);
            #pragma unroll
            for (int i = 0; i < 4; ++i)
                if (base + i < d) acc = fmaf(__int_as_float(ed[i].y), tv[i], acc);
        }
        if (j < FSUP)
            __builtin_nontemporal_store(f2bf(fmaxf(acc, 0.f)),
                                        &Xu[(size_t)n * 512 + colOff + j]);
        else if (k == 4 && j < 112)
            __builtin_nontemporal_store((ushort)0, &Xu[(size_t)n * 512 + 400 + j]);
    } else {
        // V direction: avg degree 8, batch 8
        const int n = (half - NU / 2) * 2 + sub;
        const int g = k * NV + n;
        const int s = rowPtrV[g];
        const int e = (g == KSUP * NV - 1) ? NEDGE : rowPtrV[g + 1];
        const int d = e - s;
        float acc = 0.f;
        for (int base = 0; base < d; base += 8) {
            int2 ed[8];
            #pragma unroll
            for (int i = 0; i < 8; ++i) {
                int idx = base + i; if (idx >= d) idx = base;
                ed[i] = eV[s + idx];
            }
            float tu[8];
            #pragma unroll
            for (int i = 0; i < 8; ++i)
                tu[i] = bf2f(tmpU[(size_t)ed[i].x * 512 + colOff + jj]);
            #pragma unroll
            for (int i = 0; i < 8; ++i)
                if (base + i < d) acc = fmaf(__int_as_float(ed[i].y), tu[i], acc);
        }
        if (j < FSUP)
            __builtin_nontemporal_store(f2bf(fmaxf(acc, 0.f)),
                                        &Xv[(size_t)n * 512 + colOff + j]);
        else if (k == 4 && j < 112)
            __builtin_nontemporal_store((ushort)0, &Xv[(size_t)n * 512 + 400 + j]);
    }
}

// ---------------------------------------------------------------------------
// final decoder: basis[b] = dot(bf16 Ub[u][b*128..], bf16 embV[v]); out = basis@cls
__global__ __launch_bounds__(256) void dec_k(
    const int* __restrict__ ue, const int* __restrict__ ie,
    const ushort* __restrict__ Ub, const ushort* __restrict__ embV,
    const float* __restrict__ cls, float* __restrict__ out, int nE)
{
    int e = blockIdx.x * 8 + (threadIdx.x >> 5);
    if (e >= nE) return;
    int lane = threadIdx.x & 31;
    int u = ue[e], v = ie[e];
    const ushort* pv = embV + (size_t)v * DENC;
    float vb[4];
    #pragma unroll
    for (int i = 0; i < 4; ++i) vb[i] = bf2f(pv[lane + i * 32]);
    float basis[NBAS];
    #pragma unroll
    for (int b = 0; b < NBAS; ++b) {
        const ushort* pu = Ub + (size_t)u * (NBAS * DENC) + b * DENC;
        float s = 0.f;
        #pragma unroll
        for (int i = 0; i < 4; ++i) s += bf2f(pu[lane + i * 32]) * vb[i];
        #pragma unroll
        for (int off = 16; off; off >>= 1) s += __shfl_xor(s, off, 32);
        basis[b] = s;
    }
    if (lane < NCLS) {
        float o = 0.f;
        #pragma unroll
        for (int b = 0; b < NBAS; ++b) o += basis[b] * cls[b * NCLS + lane];
        out[(size_t)e * NCLS + lane] = o;
    }
}

// ---------------------------------------------------------------------------
extern "C" void kernel_launch(void* const* d_in, const int* in_sizes, int n_in,
                              void* d_out, int out_size, void* d_ws, size_t ws_size,
                              hipStream_t stream) {
    const int*   sup_u  = (const int*)  d_in[0];
    const int*   sup_i  = (const int*)  d_in[1];
    const float* sup_v  = (const float*)d_in[2];
    const float* u_in   = (const float*)d_in[3];
    const float* v_in   = (const float*)d_in[4];
    const float* u_side = (const float*)d_in[5];
    const float* v_side = (const float*)d_in[6];
    const int*   ue     = (const int*)  d_in[7];
    const int*   ie     = (const int*)  d_in[8];
    const float* W_enc  = (const float*)d_in[9];
    const float* Wu1    = (const float*)d_in[10];
    const float* bu1    = (const float*)d_in[11];
    const float* Wi1    = (const float*)d_in[12];
    const float* bi1    = (const float*)d_in[13];
    const float* Wu2    = (const float*)d_in[14];
    const float* Wi2    = (const float*)d_in[15];
    const float* dec_W  = (const float*)d_in[16];
    const float* deccls = (const float*)d_in[17];

    char* ws = (char*)d_ws;
    // Region @0 (timeline-overlaid):
    //   ph1-2: u_bf [NU][512] bf16 @0 (102.4M), v_bf [NV][512] @102.4M (51.2M)
    //   ph3+ : Xu @0, Xv @102.4M (written by agg after u_bf dead)
    //   ph6  : embUbf @0 (25.6M, after dense2 U done), Ub bf16 @26M (76.8M)
    ushort* u_bf   = (ushort*)(ws);
    ushort* v_bf   = (ushort*)(ws + 102400000LL);
    ushort* Xu     = (ushort*)(ws);
    ushort* Xv     = (ushort*)(ws + 102400000LL);
    ushort* embUbf = (ushort*)(ws);
    ushort* Ub     = (ushort*)(ws + 26000000LL);
    // CSR region @156M (dead after agg):
    int*    histU  = (int*)(ws + 156000000LL);          // [5][NU]
    int*    histV  = (int*)(ws + 158000000LL);          // [5][NV]
    int*    rowPtrU= (int*)(ws + 159000000LL);          // [5][NU]
    int*    rowPtrV= (int*)(ws + 161000000LL);          // [5][NV]
    int*    posU   = (int*)(ws + 162000000LL);          // [5][NU]
    int*    posV   = (int*)(ws + 164000000LL);          // [5][NV]
    int*    bsums  = (int*)(ws + 165000000LL);          // 1024
    int2*   eU     = (int2*)(ws + 165010000LL);         // [2M] packed (idx,val)
    int2*   eV     = (int2*)(ws + 181010000LL);         // [2M] ends 197.01M
    // Post-agg region (over dead CSR):
    float*  sideU  = (float*)(ws + 200000000LL);        // [NU][64]
    float*  sideV  = (float*)(ws + 226000000LL);        // [NV][64]
    float*  embU   = (float*)(ws + 240000000LL);        // [NU][128] f32
    // tmp region @300M (live ph2..agg; embV/embVbf overlay after)
    ushort* tmpU   = (ushort*)(ws + 300000000LL);       // [NU][512] bf16
    ushort* tmpV   = (ushort*)(ws + 402400000LL);       // [NV][512] bf16
    float*  embV   = (float*)(ws + 300000000LL);        // [NV][128] f32 (ends 325.6M)
    ushort* embVbf = (ushort*)(ws + 326000000LL);       // [NV][128] bf16 (12.8M)
    // weights @453.6M:
    ushort* WencT  = (ushort*)(ws + 453600000LL);       // [512][512]
    ushort* W2uaT  = (ushort*)(ws + 454124288LL);       // [128][512]
    ushort* W2iaT  = (ushort*)(ws + 454255360LL);       // [128][512]
    ushort* decWT  = (ushort*)(ws + 454386432LL);       // [384][128]

    dim3 blk(256);
    const int gu128 = (NU + 127) / 128;   // 782
    const int gv128 = (NV + 127) / 128;   // 391
    const int gu64  = (NU + 63) / 64;     // 1563
    const int gv64  = (NV + 63) / 64;     // 782
    const int gE    = (NEDGE + 255) / 256;

    // ---- phase 1: bf16 conversions + CSR build ----
    cvt_k<<<dim3((NU * 512 / 4 + 255) / 256), blk, 0, stream>>>(u_in, u_bf, (long)NU * 512);
    cvt_k<<<dim3((NV * 512 / 4 + 255) / 256), blk, 0, stream>>>(v_in, v_bf, (long)NV * 512);
    cvt_wencT_k<<<dim3(512 * 512 / 256), blk, 0, stream>>>(W_enc, WencT);
    cvt_w2aT_k<<<dim3(128 * 512 / 256), blk, 0, stream>>>(Wu2, W2uaT);
    cvt_w2aT_k<<<dim3(128 * 512 / 256), blk, 0, stream>>>(Wi2, W2iaT);
    cvt_decWT_k<<<dim3(384 * 128 / 256), blk, 0, stream>>>(dec_W, decWT);

    hipMemsetAsync(histU, 0, 3000000LL, stream);   // histU + histV contiguous
    hist_k<<<dim3(gE), blk, 0, stream>>>(sup_u, sup_i, histU, histV);
    scan_reduce_k<<<dim3(245), blk, 0, stream>>>(histU, bsums, KSUP * NU);
    scan_bs_k<<<dim3(1), blk, 0, stream>>>(bsums, 245);
    scan_write_k<<<dim3(245), blk, 0, stream>>>(histU, bsums, rowPtrU, KSUP * NU);
    scan_reduce_k<<<dim3(123), blk, 0, stream>>>(histV, bsums, KSUP * NV);
    scan_bs_k<<<dim3(1), blk, 0, stream>>>(bsums, 123);
    scan_write_k<<<dim3(123), blk, 0, stream>>>(histV, bsums, rowPtrV, KSUP * NV);
    hipMemcpyAsync(posU, rowPtrU, (size_t)KSUP * NU * 4, hipMemcpyDeviceToDevice, stream);
    hipMemcpyAsync(posV, rowPtrV, (size_t)KSUP * NV * 4, hipMemcpyDeviceToDevice, stream);
    scatter_k<<<dim3(gE), blk, 0, stream>>>(sup_u, sup_i, sup_v, posU, posV, eU, eV);

    // ---- phase 2: fused encoder GEMMs (bf16 out) ----
    gemm_bf16_k<1><<<dim3(gu128, 4), blk, 0, stream>>>(u_bf, WencT, tmpU, NU, 512, 512, 512);
    gemm_bf16_k<1><<<dim3(gv128, 4), blk, 0, stream>>>(v_bf, WencT, tmpV, NV, 512, 512, 512);

    // ---- phase 3: CSR aggregation (all supports), writes packed relu'd X ----
    agg_csr_k<<<dim3(NU / 2 + NV / 2, KSUP), blk, 0, stream>>>(
        rowPtrU, eU, rowPtrV, eV, tmpU, tmpV, Xu, Xv);

    // ---- phase 4: side dense (fp32) ----
    gemm_side_k<<<dim3(gu64), blk, 0, stream>>>(u_side, Wu1, bu1, sideU, NU, HSIDE, DSIDE);
    gemm_side_k<<<dim3(gv64), blk, 0, stream>>>(v_side, Wi1, bi1, sideV, NV, HSIDE, DSIDE);

    // ---- phase 5: dense2 = X @ W2aT (MFMA) + side part (emits bf16) ----
    gemm_bf16_k<0><<<dim3(gu128, 1), blk, 0, stream>>>(Xu, W2uaT, embU, NU, 128, 512, 128);
    gemm_bf16_k<0><<<dim3(gv128, 1), blk, 0, stream>>>(Xv, W2iaT, embV, NV, 128, 512, 128);
    accum_side_k<1><<<dim3((NV + 1) / 2), blk, 0, stream>>>(sideV, Wi2, embV, embVbf, NV);
    accum_side_k<1><<<dim3((NU + 1) / 2), blk, 0, stream>>>(sideU, Wu2, embU, embUbf, NU);

    // ---- phase 6: decoder precompute Ub (bf16 out) ----
    gemm_bf16_k<1><<<dim3(gu128, 3), blk, 0, stream>>>(embUbf, decWT, Ub, NU, 384, 128, 384);

    // ---- phase 7: final decoder over edges ----
    dec_k<<<dim3(NE / 8), blk, 0, stream>>>(ue, ie, Ub, embVbf, deccls, (float*)d_out, NE);
}

// Round 6
// 1718.044 us; speedup vs baseline: 1.3236x; 1.1170x over previous
//
#include <hip/hip_runtime.h>

// Problem constants (fixed by the reference)
#define NU 100000
#define NV 50000
#define KSUP 5
#define ESUP 400000
#define NEDGE (KSUP * ESUP)   // 2,000,000
#define NE 500000
#define DIN 512
#define DGCN 500
#define FSUP 100     // DGCN / KSUP
#define DSIDE 128
#define HSIDE 64
#define DENC 128
#define NBAS 3
#define NCLS 5

__device__ __forceinline__ ushort f2bf(float x) {
    union { float f; unsigned u; } c; c.f = x;
    unsigned r = (c.u + 0x7FFFu + ((c.u >> 16) & 1u)) >> 16;   // RNE
    return (ushort)r;
}
__device__ __forceinline__ float bf2f(ushort h) {
    union { unsigned u; float f; } c; c.u = ((unsigned)h) << 16;
    return c.f;
}
// unpack a u32 holding two bf16 (lo = even col, hi = odd col)
__device__ __forceinline__ float lof(uint g) { return __uint_as_float(g << 16); }
__device__ __forceinline__ float hif(uint g) { return __uint_as_float(g & 0xffff0000u); }

typedef __attribute__((ext_vector_type(4))) float f32x4;
typedef __attribute__((ext_vector_type(8))) short bf16x8;
typedef __attribute__((address_space(3))) void lds_void;
typedef const __attribute__((address_space(1))) void glob_void;

// ---------------------------------------------------------------------------
// bf16 MFMA GEMM: C[M,N] = A[M,K](bf16,K-major) @ BT[N,K](bf16,K-major)^T
// 128x128 tile, BK=64, 4 waves (2x2). LDS XOR-swizzled via pre-swizzled
// global source (rule #21). STORE_BF16: 1 -> C ushort, 0 -> C float.
template<int STORE_BF16>
__global__ __launch_bounds__(256) void gemm_bf16_k(
    const ushort* __restrict__ A, const ushort* __restrict__ BT,
    void* __restrict__ Cout, int M, int N, int K, int ldc)
{
    __shared__ ushort As[128 * 64];
    __shared__ ushort Bs[128 * 64];
    const int t = threadIdx.x;
    const int lane = t & 63;
    const int w = t >> 6;
    const int wr = w >> 1, wc = w & 1;
    const int rowBase = blockIdx.x * 128;
    const int colBase = blockIdx.y * 128;

    f32x4 acc[4][4] = {};

    for (int k0 = 0; k0 < K; k0 += 64) {
        #pragma unroll
        for (int i = 0; i < 4; ++i) {
            int chi = i * 256 + t;
            int r = chi >> 3;
            int c = (((chi >> 3) & 7) ^ (chi & 7)) * 8;
            int ga = rowBase + r; if (ga > M - 1) ga = M - 1;
            __builtin_amdgcn_global_load_lds(
                (glob_void*)(A + (size_t)ga * K + k0 + c),
                (lds_void*)(As + (size_t)chi * 8), 16, 0, 0);
            int gb = colBase + r; if (gb > N - 1) gb = N - 1;
            __builtin_amdgcn_global_load_lds(
                (glob_void*)(BT + (size_t)gb * K + k0 + c),
                (lds_void*)(Bs + (size_t)chi * 8), 16, 0, 0);
        }
        __syncthreads();

        #pragma unroll
        for (int kk = 0; kk < 2; ++kk) {
            bf16x8 af[4], bfr[4];
            const int cb2 = (kk * 32 + (lane >> 4) * 8) * 2;
            #pragma unroll
            for (int mi = 0; mi < 4; ++mi) {
                int r = wr * 64 + mi * 16 + (lane & 15);
                int off = (r * 128 + cb2) ^ ((r & 7) << 4);
                af[mi] = *(const bf16x8*)((const char*)As + off);
            }
            #pragma unroll
            for (int nj = 0; nj < 4; ++nj) {
                int r = wc * 64 + nj * 16 + (lane & 15);
                int off = (r * 128 + cb2) ^ ((r & 7) << 4);
                bfr[nj] = *(const bf16x8*)((const char*)Bs + off);
            }
            #pragma unroll
            for (int mi = 0; mi < 4; ++mi)
                #pragma unroll
                for (int nj = 0; nj < 4; ++nj)
                    acc[mi][nj] = __builtin_amdgcn_mfma_f32_16x16x32_bf16(
                        af[mi], bfr[nj], acc[mi][nj], 0, 0, 0);
        }
        __syncthreads();
    }

    #pragma unroll
    for (int mi = 0; mi < 4; ++mi) {
        #pragma unroll
        for (int q = 0; q < 4; ++q) {
            int gr = rowBase + wr * 64 + mi * 16 + (lane >> 4) * 4 + q;
            if (gr >= M) continue;
            #pragma unroll
            for (int nj = 0; nj < 4; ++nj) {
                int gc = colBase + wc * 64 + nj * 16 + (lane & 15);
                float v = acc[mi][nj][q];
                if (STORE_BF16)
                    ((ushort*)Cout)[(size_t)gr * ldc + gc] = f2bf(v);
                else
                    ((float*)Cout)[(size_t)gr * ldc + gc] = v;
            }
        }
    }
}

// ---------------------------------------------------------------------------
// fp32 tiled GEMM (side dense only): C = relu(A@B + bias)
#define BM 64
#define BN 64
#define BK 16
__global__ __launch_bounds__(256) void gemm_side_k(
    const float* __restrict__ A, const float* __restrict__ B,
    const float* __restrict__ bias, float* __restrict__ C,
    int M, int N, int K)
{
    __shared__ float As[BK][BM + 4];
    __shared__ float Bs[BK][BN + 4];
    const int t = threadIdx.x;
    const int rowBase = blockIdx.x * BM;
    const int ty = t >> 4, tx = t & 15;
    float acc[4][4] = {};

    for (int k0 = 0; k0 < K; k0 += BK) {
        #pragma unroll
        for (int p = 0; p < 4; ++p) {
            int r = p * 16 + (t >> 4), kk = t & 15;
            int gr = rowBase + r, gk = k0 + kk;
            As[kk][r] = (gr < M && gk < K) ? A[(size_t)gr * K + gk] : 0.f;
        }
        #pragma unroll
        for (int p = 0; p < 4; ++p) {
            int kk = p * 4 + (t >> 6), j = t & 63;
            int gk = k0 + kk;
            Bs[kk][j] = (j < N && gk < K) ? B[(size_t)gk * N + j] : 0.f;
        }
        __syncthreads();
        #pragma unroll
        for (int kk = 0; kk < BK; ++kk) {
            float4 a4 = *reinterpret_cast<const float4*>(&As[kk][ty * 4]);
            float4 b4 = *reinterpret_cast<const float4*>(&Bs[kk][tx * 4]);
            float aa[4] = {a4.x, a4.y, a4.z, a4.w};
            float bb[4] = {b4.x, b4.y, b4.z, b4.w};
            #pragma unroll
            for (int i = 0; i < 4; ++i)
                #pragma unroll
                for (int j = 0; j < 4; ++j)
                    acc[i][j] = fmaf(aa[i], bb[j], acc[i][j]);
        }
        __syncthreads();
    }
    #pragma unroll
    for (int i = 0; i < 4; ++i) {
        int gr = rowBase + ty * 4 + i;
        if (gr >= M) continue;
        #pragma unroll
        for (int j = 0; j < 4; ++j) {
            int gc = tx * 4 + j;
            if (gc < N) C[(size_t)gr * N + gc] = fmaxf(acc[i][j] + bias[gc], 0.f);
        }
    }
}

// ---------------------------------------------------------------------------
// conversions
__global__ __launch_bounds__(256) void cvt_k(const float* __restrict__ in,
                                             ushort* __restrict__ out, long n) {
    long i = ((long)blockIdx.x * 256 + threadIdx.x) * 4;
    if (i >= n) return;
    float4 v = *(const float4*)(in + i);
    ushort4 o;
    o.x = f2bf(v.x); o.y = f2bf(v.y); o.z = f2bf(v.z); o.w = f2bf(v.w);
    *(ushort4*)(out + i) = o;
}

__global__ __launch_bounds__(256) void cvt_wencT_k(const float* __restrict__ W,
                                                   ushort* __restrict__ out) {
    int idx = blockIdx.x * 256 + threadIdx.x;
    int c = idx >> 9, d = idx & 511;
    float v = 0.f;
    if (c < DGCN) {
        int s = c / FSUP, f = c - s * FSUP;
        v = W[((size_t)s * DIN + d) * FSUP + f];
    }
    out[idx] = f2bf(v);
}

__global__ __launch_bounds__(256) void cvt_w2aT_k(const float* __restrict__ W2,
                                                  ushort* __restrict__ out) {
    int idx = blockIdx.x * 256 + threadIdx.x;
    int j = idx >> 9, c = idx & 511;
    float v = (c < DGCN) ? W2[(size_t)c * DENC + j] : 0.f;
    out[idx] = f2bf(v);
}

__global__ __launch_bounds__(256) void cvt_decWT_k(const float* __restrict__ W,
                                                   ushort* __restrict__ out) {
    int idx = blockIdx.x * 256 + threadIdx.x;       // 384*128
    int p = idx >> 7, k = idx & 127;
    int b = p >> 7, j = p & 127;
    out[idx] = f2bf(W[((size_t)b * DENC + k) * DENC + j]);
}

// emb[n][j] (+= side part); OUT_BF16 selects bf16 vs f32 destination
template<int OUT_BF16>
__global__ __launch_bounds__(256) void accum_side_k(const float* __restrict__ side,
                                                    const float* __restrict__ W2,
                                                    const float* __restrict__ embIn,
                                                    void* __restrict__ embOut, int M) {
    __shared__ float Ws[HSIDE][DENC];
    for (int i = threadIdx.x; i < HSIDE * DENC; i += 256)
        Ws[i >> 7][i & 127] = W2[(size_t)(DGCN + (i >> 7)) * DENC + (i & 127)];
    __syncthreads();
    int n = blockIdx.x * 2 + (threadIdx.x >> 7);
    if (n >= M) return;
    int j = threadIdx.x & 127;
    const float* s = side + (size_t)n * HSIDE;
    float a = embIn[(size_t)n * DENC + j];
    #pragma unroll 8
    for (int h = 0; h < HSIDE; ++h) a = fmaf(s[h], Ws[h][j], a);
    if (OUT_BF16) ((ushort*)embOut)[(size_t)n * DENC + j] = f2bf(a);
    else          ((float*)embOut)[(size_t)n * DENC + j] = a;
}

// ---------------------------------------------------------------------------
// CSR build: histogram, 3-kernel exclusive scan, scatter (packed int2)
__global__ __launch_bounds__(256) void hist_k(
    const int* __restrict__ su, const int* __restrict__ si,
    int* __restrict__ histU, int* __restrict__ histV)
{
    int e = blockIdx.x * 256 + threadIdx.x;
    if (e >= NEDGE) return;
    int k = e / ESUP;
    atomicAdd(&histU[k * NU + su[e]], 1);
    atomicAdd(&histV[k * NV + si[e]], 1);
}

__global__ __launch_bounds__(256) void scan_reduce_k(const int* __restrict__ in,
                                                     int* __restrict__ bs, int n) {
    __shared__ int sm[256];
    int base = blockIdx.x * 2048 + threadIdx.x * 8;
    int s = 0;
    #pragma unroll
    for (int i = 0; i < 8; ++i) { int idx = base + i; if (idx < n) s += in[idx]; }
    sm[threadIdx.x] = s; __syncthreads();
    for (int off = 128; off; off >>= 1) {
        if (threadIdx.x < off) sm[threadIdx.x] += sm[threadIdx.x + off];
        __syncthreads();
    }
    if (threadIdx.x == 0) bs[blockIdx.x] = sm[0];
}

// single block: exclusive scan of bs[0..nb), nb <= 256
__global__ __launch_bounds__(256) void scan_bs_k(int* __restrict__ bs, int nb) {
    __shared__ int sm[256];
    int t = threadIdx.x;
    int v = (t < nb) ? bs[t] : 0;
    sm[t] = v; __syncthreads();
    for (int off = 1; off < 256; off <<= 1) {
        int add = (t >= off) ? sm[t - off] : 0;
        __syncthreads();
        sm[t] += add;
        __syncthreads();
    }
    if (t < nb) bs[t] = sm[t] - v;   // exclusive
}

__global__ __launch_bounds__(256) void scan_write_k(const int* __restrict__ in,
                                                    const int* __restrict__ bs,
                                                    int* __restrict__ out, int n) {
    __shared__ int sm[256];
    int t = threadIdx.x;
    int base = blockIdx.x * 2048 + t * 8;
    int loc[8]; int s = 0;
    #pragma unroll
    for (int i = 0; i < 8; ++i) {
        int idx = base + i;
        loc[i] = (idx < n) ? in[idx] : 0;
        s += loc[i];
    }
    sm[t] = s; __syncthreads();
    int sv = s;
    for (int off = 1; off < 256; off <<= 1) {
        int add = (t >= off) ? sm[t - off] : 0;
        __syncthreads();
        sm[t] += add;
        __syncthreads();
    }
    int thOff = bs[blockIdx.x] + sm[t] - sv;
    int run = 0;
    #pragma unroll
    for (int i = 0; i < 8; ++i) {
        int idx = base + i;
        if (idx < n) out[idx] = thOff + run;
        run += loc[i];
    }
}

// packed scatter: one 8B (idx, valbits) write per direction per edge
__global__ __launch_bounds__(256) void scatter_k(
    const int* __restrict__ su, const int* __restrict__ si,
    const float* __restrict__ sv,
    int* __restrict__ posU, int* __restrict__ posV,
    int2* __restrict__ eU, int2* __restrict__ eV)
{
    int e = blockIdx.x * 256 + threadIdx.x;
    if (e >= NEDGE) return;
    int k = e / ESUP;
    int r = su[e], c = si[e];
    int vb = __float_as_int(sv[e]);
    int pu = atomicAdd(&posU[k * NU + r], 1);
    eU[pu] = make_int2(c, vb);
    int pv = atomicAdd(&posV[k * NV + c], 1);
    eV[pv] = make_int2(r, vb);
}

// ---------------------------------------------------------------------------
// CSR aggregation, all supports (blockIdx.y = k), both directions.
// ONE wave per (node, k): lane l covers cols 2l,2l+1 via one u32 gather
// (lanes 0..49 active). Batched edge loads for MLP; NT packed-u32 stores.
__global__ __launch_bounds__(256) void agg_csr_k(
    const int* __restrict__ rowPtrU, const int2* __restrict__ eU,
    const int* __restrict__ rowPtrV, const int2* __restrict__ eV,
    const ushort* __restrict__ tmpU, const ushort* __restrict__ tmpV,
    ushort* __restrict__ Xu, ushort* __restrict__ Xv)
{
    const int k = blockIdx.y;
    const int lane = threadIdx.x & 63;
    const int wv = blockIdx.x * 4 + (threadIdx.x >> 6);   // global wave id
    const int ll = (lane < 50) ? lane : 49;
    const int colOff = k * FSUP;

    if (wv < NU) {
        // U direction: avg degree 4, batch 4
        const int n = wv;
        const int g = k * NU + n;
        const int s = rowPtrU[g];
        const int e = (g == KSUP * NU - 1) ? NEDGE : rowPtrU[g + 1];
        const int d = e - s;
        float a0 = 0.f, a1 = 0.f;
        for (int base = 0; base < d; base += 4) {
            int2 ed[4];
            #pragma unroll
            for (int i = 0; i < 4; ++i) {
                int idx = base + i; if (idx >= d) idx = base;
                ed[i] = eU[s + idx];
            }
            uint gw[4];
            #pragma unroll
            for (int i = 0; i < 4; ++i)
                gw[i] = *((const uint*)(tmpV + (size_t)ed[i].x * 512 + colOff) + ll);
            #pragma unroll
            for (int i = 0; i < 4; ++i) {
                if (base + i < d) {
                    float v = __int_as_float(ed[i].y);
                    a0 = fmaf(v, lof(gw[i]), a0);
                    a1 = fmaf(v, hif(gw[i]), a1);
                }
            }
        }
        uint payload = (uint)f2bf(fmaxf(a0, 0.f)) | ((uint)f2bf(fmaxf(a1, 0.f)) << 16);
        if (lane < 50)
            __builtin_nontemporal_store(payload,
                (uint*)(Xu + (size_t)n * 512 + colOff) + lane);
        else if (k == 4 && lane < 56)
            __builtin_nontemporal_store(0u,
                (uint*)(Xu + (size_t)n * 512 + 500 + 2 * (lane - 50)));
    } else {
        // V direction: avg degree 8, batch 8
        const int n = wv - NU;
        const int g = k * NV + n;
        const int s = rowPtrV[g];
        const int e = (g == KSUP * NV - 1) ? NEDGE : rowPtrV[g + 1];
        const int d = e - s;
        float a0 = 0.f, a1 = 0.f;
        for (int base = 0; base < d; base += 8) {
            int2 ed[8];
            #pragma unroll
            for (int i = 0; i < 8; ++i) {
                int idx = base + i; if (idx >= d) idx = base;
                ed[i] = eV[s + idx];
            }
            uint gw[8];
            #pragma unroll
            for (int i = 0; i < 8; ++i)
                gw[i] = *((const uint*)(tmpU + (size_t)ed[i].x * 512 + colOff) + ll);
            #pragma unroll
            for (int i = 0; i < 8; ++i) {
                if (base + i < d) {
                    float v = __int_as_float(ed[i].y);
                    a0 = fmaf(v, lof(gw[i]), a0);
                    a1 = fmaf(v, hif(gw[i]), a1);
                }
            }
        }
        uint payload = (uint)f2bf(fmaxf(a0, 0.f)) | ((uint)f2bf(fmaxf(a1, 0.f)) << 16);
        if (lane < 50)
            __builtin_nontemporal_store(payload,
                (uint*)(Xv + (size_t)n * 512 + colOff) + lane);
        else if (k == 4 && lane < 56)
            __builtin_nontemporal_store(0u,
                (uint*)(Xv + (size_t)n * 512 + 500 + 2 * (lane - 50)));
    }
}

// ---------------------------------------------------------------------------
// final decoder: u32 gathers (8 per edge) issued up-front, interleaved
// 3-chain shuffle reduce. basis[b] = dot(Ub[u][b], embV[v]); out = basis@cls
__global__ __launch_bounds__(256) void dec_k(
    const int* __restrict__ ue, const int* __restrict__ ie,
    const ushort* __restrict__ Ub, const ushort* __restrict__ embV,
    const float* __restrict__ cls, float* __restrict__ out, int nE)
{
    int e = blockIdx.x * 8 + (threadIdx.x >> 5);
    if (e >= nE) return;
    int lane = threadIdx.x & 31;
    int u = ue[e], v = ie[e];
    const uint* pv = (const uint*)(embV + (size_t)v * DENC);   // 64 u32
    const uint* pu = (const uint*)(Ub + (size_t)u * (NBAS * DENC)); // 192 u32
    uint v0 = pv[lane], v1 = pv[lane + 32];
    uint b0[NBAS], b1[NBAS];
    #pragma unroll
    for (int b = 0; b < NBAS; ++b) {
        b0[b] = pu[b * 64 + lane];
        b1[b] = pu[b * 64 + 32 + lane];
    }
    float v0l = lof(v0), v0h = hif(v0), v1l = lof(v1), v1h = hif(v1);
    float s[NBAS];
    #pragma unroll
    for (int b = 0; b < NBAS; ++b) {
        float t = lof(b0[b]) * v0l;
        t = fmaf(hif(b0[b]), v0h, t);
        t = fmaf(lof(b1[b]), v1l, t);
        s[b] = fmaf(hif(b1[b]), v1h, t);
    }
    #pragma unroll
    for (int off = 16; off; off >>= 1)
        #pragma unroll
        for (int b = 0; b < NBAS; ++b) s[b] += __shfl_xor(s[b], off, 32);
    if (lane < NCLS) {
        float o = 0.f;
        #pragma unroll
        for (int b = 0; b < NBAS; ++b) o += s[b] * cls[b * NCLS + lane];
        out[(size_t)e * NCLS + lane] = o;
    }
}

// ---------------------------------------------------------------------------
extern "C" void kernel_launch(void* const* d_in, const int* in_sizes, int n_in,
                              void* d_out, int out_size, void* d_ws, size_t ws_size,
                              hipStream_t stream) {
    const int*   sup_u  = (const int*)  d_in[0];
    const int*   sup_i  = (const int*)  d_in[1];
    const float* sup_v  = (const float*)d_in[2];
    const float* u_in   = (const float*)d_in[3];
    const float* v_in   = (const float*)d_in[4];
    const float* u_side = (const float*)d_in[5];
    const float* v_side = (const float*)d_in[6];
    const int*   ue     = (const int*)  d_in[7];
    const int*   ie     = (const int*)  d_in[8];
    const float* W_enc  = (const float*)d_in[9];
    const float* Wu1    = (const float*)d_in[10];
    const float* bu1    = (const float*)d_in[11];
    const float* Wi1    = (const float*)d_in[12];
    const float* bi1    = (const float*)d_in[13];
    const float* Wu2    = (const float*)d_in[14];
    const float* Wi2    = (const float*)d_in[15];
    const float* dec_W  = (const float*)d_in[16];
    const float* deccls = (const float*)d_in[17];

    char* ws = (char*)d_ws;
    ushort* u_bf   = (ushort*)(ws);
    ushort* v_bf   = (ushort*)(ws + 102400000LL);
    ushort* Xu     = (ushort*)(ws);
    ushort* Xv     = (ushort*)(ws + 102400000LL);
    ushort* embUbf = (ushort*)(ws);
    ushort* Ub     = (ushort*)(ws + 26000000LL);
    // CSR region @156M (dead after agg):
    int*    histU  = (int*)(ws + 156000000LL);          // [5][NU]
    int*    histV  = (int*)(ws + 158000000LL);          // [5][NV]
    int*    rowPtrU= (int*)(ws + 159000000LL);          // [5][NU]
    int*    rowPtrV= (int*)(ws + 161000000LL);          // [5][NV]
    int*    posU   = (int*)(ws + 162000000LL);          // [5][NU]
    int*    posV   = (int*)(ws + 164000000LL);          // [5][NV]
    int*    bsums  = (int*)(ws + 165000000LL);          // 1024
    int2*   eU     = (int2*)(ws + 165010000LL);         // [2M] packed (idx,val)
    int2*   eV     = (int2*)(ws + 181010000LL);         // [2M] ends 197.01M
    // Post-agg region (over dead CSR):
    float*  sideU  = (float*)(ws + 200000000LL);        // [NU][64]
    float*  sideV  = (float*)(ws + 226000000LL);        // [NV][64]
    float*  embU   = (float*)(ws + 240000000LL);        // [NU][128] f32
    // tmp region @300M (live ph2..agg; embV/embVbf overlay after)
    ushort* tmpU   = (ushort*)(ws + 300000000LL);       // [NU][512] bf16
    ushort* tmpV   = (ushort*)(ws + 402400000LL);       // [NV][512] bf16
    float*  embV   = (float*)(ws + 300000000LL);        // [NV][128] f32
    ushort* embVbf = (ushort*)(ws + 326000000LL);       // [NV][128] bf16
    // weights @453.6M:
    ushort* WencT  = (ushort*)(ws + 453600000LL);       // [512][512]
    ushort* W2uaT  = (ushort*)(ws + 454124288LL);       // [128][512]
    ushort* W2iaT  = (ushort*)(ws + 454255360LL);       // [128][512]
    ushort* decWT  = (ushort*)(ws + 454386432LL);       // [384][128]

    dim3 blk(256);
    const int gu128 = (NU + 127) / 128;   // 782
    const int gv128 = (NV + 127) / 128;   // 391
    const int gu64  = (NU + 63) / 64;     // 1563
    const int gv64  = (NV + 63) / 64;     // 782
    const int gE    = (NEDGE + 255) / 256;

    // ---- phase 1: bf16 conversions + CSR build ----
    cvt_k<<<dim3((NU * 512 / 4 + 255) / 256), blk, 0, stream>>>(u_in, u_bf, (long)NU * 512);
    cvt_k<<<dim3((NV * 512 / 4 + 255) / 256), blk, 0, stream>>>(v_in, v_bf, (long)NV * 512);
    cvt_wencT_k<<<dim3(512 * 512 / 256), blk, 0, stream>>>(W_enc, WencT);
    cvt_w2aT_k<<<dim3(128 * 512 / 256), blk, 0, stream>>>(Wu2, W2uaT);
    cvt_w2aT_k<<<dim3(128 * 512 / 256), blk, 0, stream>>>(Wi2, W2iaT);
    cvt_decWT_k<<<dim3(384 * 128 / 256), blk, 0, stream>>>(dec_W, decWT);

    hipMemsetAsync(histU, 0, 3000000LL, stream);   // histU + histV contiguous
    hist_k<<<dim3(gE), blk, 0, stream>>>(sup_u, sup_i, histU, histV);
    scan_reduce_k<<<dim3(245), blk, 0, stream>>>(histU, bsums, KSUP * NU);
    scan_bs_k<<<dim3(1), blk, 0, stream>>>(bsums, 245);
    scan_write_k<<<dim3(245), blk, 0, stream>>>(histU, bsums, rowPtrU, KSUP * NU);
    scan_reduce_k<<<dim3(123), blk, 0, stream>>>(histV, bsums, KSUP * NV);
    scan_bs_k<<<dim3(1), blk, 0, stream>>>(bsums, 123);
    scan_write_k<<<dim3(123), blk, 0, stream>>>(histV, bsums, rowPtrV, KSUP * NV);
    hipMemcpyAsync(posU, rowPtrU, (size_t)KSUP * NU * 4, hipMemcpyDeviceToDevice, stream);
    hipMemcpyAsync(posV, rowPtrV, (size_t)KSUP * NV * 4, hipMemcpyDeviceToDevice, stream);
    scatter_k<<<dim3(gE), blk, 0, stream>>>(sup_u, sup_i, sup_v, posU, posV, eU, eV);

    // ---- phase 2: fused encoder GEMMs (bf16 out) ----
    gemm_bf16_k<1><<<dim3(gu128, 4), blk, 0, stream>>>(u_bf, WencT, tmpU, NU, 512, 512, 512);
    gemm_bf16_k<1><<<dim3(gv128, 4), blk, 0, stream>>>(v_bf, WencT, tmpV, NV, 512, 512, 512);

    // ---- phase 3: CSR aggregation (1 wave/node/support), packed relu'd X ----
    agg_csr_k<<<dim3((NU + NV) / 4, KSUP), blk, 0, stream>>>(
        rowPtrU, eU, rowPtrV, eV, tmpU, tmpV, Xu, Xv);

    // ---- phase 4: side dense (fp32) ----
    gemm_side_k<<<dim3(gu64), blk, 0, stream>>>(u_side, Wu1, bu1, sideU, NU, HSIDE, DSIDE);
    gemm_side_k<<<dim3(gv64), blk, 0, stream>>>(v_side, Wi1, bi1, sideV, NV, HSIDE, DSIDE);

    // ---- phase 5: dense2 = X @ W2aT (MFMA) + side part (emits bf16) ----
    gemm_bf16_k<0><<<dim3(gu128, 1), blk, 0, stream>>>(Xu, W2uaT, embU, NU, 128, 512, 128);
    gemm_bf16_k<0><<<dim3(gv128, 1), blk, 0, stream>>>(Xv, W2iaT, embV, NV, 128, 512, 128);
    accum_side_k<1><<<dim3((NV + 1) / 2), blk, 0, stream>>>(sideV, Wi2, embV, embVbf, NV);
    accum_side_k<1><<<dim3((NU + 1) / 2), blk, 0, stream>>>(sideU, Wu2, embU, embUbf, NU);

    // ---- phase 6: decoder precompute Ub (bf16 out) ----
    gemm_bf16_k<1><<<dim3(gu128, 3), blk, 0, stream>>>(embUbf, decWT, Ub, NU, 384, 128, 384);

    // ---- phase 7: final decoder over edges ----
    dec_k<<<dim3(NE / 8), blk, 0, stream>>>(ue, ie, Ub, embVbf, deccls, (float*)d_out, NE);
}

// Round 7
// 1403.646 us; speedup vs baseline: 1.6201x; 1.2240x over previous
//
#include <hip/hip_runtime.h>

// Problem constants (fixed by the reference)
#define NU 100000
#define NV 50000
#define KSUP 5
#define ESUP 400000
#define NEDGE (KSUP * ESUP)   // 2,000,000
#define NE 500000
#define DIN 512
#define DGCN 500
#define FSUP 100     // DGCN / KSUP
#define DSIDE 128
#define HSIDE 64
#define DENC 128
#define NBAS 3
#define NCLS 5

#define TMPW 640     // padded tmp width: 5 supports x 128 (256B-aligned slices)
#define XW 576       // X width: 500 gcn + 64 side + 12 pad (K = 9*64)

__device__ __forceinline__ ushort f2bf(float x) {
    union { float f; unsigned u; } c; c.f = x;
    unsigned r = (c.u + 0x7FFFu + ((c.u >> 16) & 1u)) >> 16;   // RNE
    return (ushort)r;
}
__device__ __forceinline__ float bf2f(ushort h) {
    union { unsigned u; float f; } c; c.u = ((unsigned)h) << 16;
    return c.f;
}
// unpack a u32 holding two bf16 (lo = even col, hi = odd col)
__device__ __forceinline__ float lof(uint g) { return __uint_as_float(g << 16); }
__device__ __forceinline__ float hif(uint g) { return __uint_as_float(g & 0xffff0000u); }

typedef __attribute__((ext_vector_type(4))) float f32x4;
typedef __attribute__((ext_vector_type(8))) short bf16x8;
typedef __attribute__((address_space(3))) void lds_void;
typedef const __attribute__((address_space(1))) void glob_void;

// ---------------------------------------------------------------------------
// bf16 MFMA GEMM: C[M,N] = A[M,K](bf16,K-major) @ BT[N,K](bf16,K-major)^T
// 128x128 tile, BK=64, 4 waves (2x2). LDS XOR-swizzled via pre-swizzled
// global source (rule #21). STORE_BF16: 1 -> C ushort, 0 -> C float.
template<int STORE_BF16>
__global__ __launch_bounds__(256) void gemm_bf16_k(
    const ushort* __restrict__ A, const ushort* __restrict__ BT,
    void* __restrict__ Cout, int M, int N, int K, int ldc)
{
    __shared__ ushort As[128 * 64];
    __shared__ ushort Bs[128 * 64];
    const int t = threadIdx.x;
    const int lane = t & 63;
    const int w = t >> 6;
    const int wr = w >> 1, wc = w & 1;
    const int rowBase = blockIdx.x * 128;
    const int colBase = blockIdx.y * 128;

    f32x4 acc[4][4] = {};

    for (int k0 = 0; k0 < K; k0 += 64) {
        #pragma unroll
        for (int i = 0; i < 4; ++i) {
            int chi = i * 256 + t;
            int r = chi >> 3;
            int c = (((chi >> 3) & 7) ^ (chi & 7)) * 8;
            int ga = rowBase + r; if (ga > M - 1) ga = M - 1;
            __builtin_amdgcn_global_load_lds(
                (glob_void*)(A + (size_t)ga * K + k0 + c),
                (lds_void*)(As + (size_t)chi * 8), 16, 0, 0);
            int gb = colBase + r; if (gb > N - 1) gb = N - 1;
            __builtin_amdgcn_global_load_lds(
                (glob_void*)(BT + (size_t)gb * K + k0 + c),
                (lds_void*)(Bs + (size_t)chi * 8), 16, 0, 0);
        }
        __syncthreads();

        #pragma unroll
        for (int kk = 0; kk < 2; ++kk) {
            bf16x8 af[4], bfr[4];
            const int cb2 = (kk * 32 + (lane >> 4) * 8) * 2;
            #pragma unroll
            for (int mi = 0; mi < 4; ++mi) {
                int r = wr * 64 + mi * 16 + (lane & 15);
                int off = (r * 128 + cb2) ^ ((r & 7) << 4);
                af[mi] = *(const bf16x8*)((const char*)As + off);
            }
            #pragma unroll
            for (int nj = 0; nj < 4; ++nj) {
                int r = wc * 64 + nj * 16 + (lane & 15);
                int off = (r * 128 + cb2) ^ ((r & 7) << 4);
                bfr[nj] = *(const bf16x8*)((const char*)Bs + off);
            }
            #pragma unroll
            for (int mi = 0; mi < 4; ++mi)
                #pragma unroll
                for (int nj = 0; nj < 4; ++nj)
                    acc[mi][nj] = __builtin_amdgcn_mfma_f32_16x16x32_bf16(
                        af[mi], bfr[nj], acc[mi][nj], 0, 0, 0);
        }
        __syncthreads();
    }

    #pragma unroll
    for (int mi = 0; mi < 4; ++mi) {
        #pragma unroll
        for (int q = 0; q < 4; ++q) {
            int gr = rowBase + wr * 64 + mi * 16 + (lane >> 4) * 4 + q;
            if (gr >= M) continue;
            #pragma unroll
            for (int nj = 0; nj < 4; ++nj) {
                int gc = colBase + wc * 64 + nj * 16 + (lane & 15);
                float v = acc[mi][nj][q];
                if (STORE_BF16)
                    ((ushort*)Cout)[(size_t)gr * ldc + gc] = f2bf(v);
                else
                    ((float*)Cout)[(size_t)gr * ldc + gc] = v;
            }
        }
    }
}

// ---------------------------------------------------------------------------
// side dense (fp32 compute): writes bf16 relu(A@B+bias) into X cols [500,564)
#define BM 64
#define BN 64
#define BK 16
__global__ __launch_bounds__(256) void gemm_side_k(
    const float* __restrict__ A, const float* __restrict__ B,
    const float* __restrict__ bias, ushort* __restrict__ X,
    int M, int K)
{
    __shared__ float As[BK][BM + 4];
    __shared__ float Bs[BK][BN + 4];
    const int t = threadIdx.x;
    const int rowBase = blockIdx.x * BM;
    const int ty = t >> 4, tx = t & 15;
    float acc[4][4] = {};

    for (int k0 = 0; k0 < K; k0 += BK) {
        #pragma unroll
        for (int p = 0; p < 4; ++p) {
            int r = p * 16 + (t >> 4), kk = t & 15;
            int gr = rowBase + r, gk = k0 + kk;
            As[kk][r] = (gr < M && gk < K) ? A[(size_t)gr * K + gk] : 0.f;
        }
        #pragma unroll
        for (int p = 0; p < 4; ++p) {
            int kk = p * 4 + (t >> 6), j = t & 63;
            int gk = k0 + kk;
            Bs[kk][j] = (j < HSIDE && gk < K) ? B[(size_t)gk * HSIDE + j] : 0.f;
        }
        __syncthreads();
        #pragma unroll
        for (int kk = 0; kk < BK; ++kk) {
            float4 a4 = *reinterpret_cast<const float4*>(&As[kk][ty * 4]);
            float4 b4 = *reinterpret_cast<const float4*>(&Bs[kk][tx * 4]);
            float aa[4] = {a4.x, a4.y, a4.z, a4.w};
            float bb[4] = {b4.x, b4.y, b4.z, b4.w};
            #pragma unroll
            for (int i = 0; i < 4; ++i)
                #pragma unroll
                for (int j = 0; j < 4; ++j)
                    acc[i][j] = fmaf(aa[i], bb[j], acc[i][j]);
        }
        __syncthreads();
    }
    #pragma unroll
    for (int i = 0; i < 4; ++i) {
        int gr = rowBase + ty * 4 + i;
        if (gr >= M) continue;
        #pragma unroll
        for (int j = 0; j < 4; ++j) {
            int gc = tx * 4 + j;
            if (gc < HSIDE)
                X[(size_t)gr * XW + 500 + gc] = f2bf(fmaxf(acc[i][j] + bias[gc], 0.f));
        }
    }
}

// ---------------------------------------------------------------------------
// conversions
__global__ __launch_bounds__(256) void cvt_k(const float* __restrict__ in,
                                             ushort* __restrict__ out, long n) {
    long i = ((long)blockIdx.x * 256 + threadIdx.x) * 4;
    if (i >= n) return;
    float4 v = *(const float4*)(in + i);
    ushort4 o;
    o.x = f2bf(v.x); o.y = f2bf(v.y); o.z = f2bf(v.z); o.w = f2bf(v.w);
    *(ushort4*)(out + i) = o;
}

// WencT2[n'][d], n' in [0,640): k=n'>>7, f=n'&127; val = f<100 ? W_enc[k][d][f] : 0
__global__ __launch_bounds__(256) void cvt_wencT2_k(const float* __restrict__ W,
                                                    ushort* __restrict__ out) {
    int idx = blockIdx.x * 256 + threadIdx.x;   // 640*512
    int np = idx >> 9, d = idx & 511;
    int k = np >> 7, f = np & 127;
    float v = (f < FSUP) ? W[((size_t)k * DIN + d) * FSUP + f] : 0.f;
    out[idx] = f2bf(v);
}

// W2fT[j][c] = bf16(W2[c][j]) for c<564, 0 for pad. out [128][576]
__global__ __launch_bounds__(256) void cvt_w2fT_k(const float* __restrict__ W2,
                                                  ushort* __restrict__ out) {
    int idx = blockIdx.x * 256 + threadIdx.x;   // 128*576
    if (idx >= DENC * XW) return;
    int j = idx / XW, c = idx - j * XW;
    float v = (c < DGCN + HSIDE) ? W2[(size_t)c * DENC + j] : 0.f;
    out[idx] = f2bf(v);
}

// ---------------------------------------------------------------------------
// CSR build: histogram, 3-kernel exclusive scan, scatter (packed u64, NT)
__global__ __launch_bounds__(256) void hist_k(
    const int* __restrict__ su, const int* __restrict__ si,
    int* __restrict__ histU, int* __restrict__ histV)
{
    int e = blockIdx.x * 256 + threadIdx.x;
    if (e >= NEDGE) return;
    int k = e / ESUP;
    atomicAdd(&histU[k * NU + su[e]], 1);
    atomicAdd(&histV[k * NV + si[e]], 1);
}

__global__ __launch_bounds__(256) void scan_reduce_k(const int* __restrict__ in,
                                                     int* __restrict__ bs, int n) {
    __shared__ int sm[256];
    int base = blockIdx.x * 2048 + threadIdx.x * 8;
    int s = 0;
    #pragma unroll
    for (int i = 0; i < 8; ++i) { int idx = base + i; if (idx < n) s += in[idx]; }
    sm[threadIdx.x] = s; __syncthreads();
    for (int off = 128; off; off >>= 1) {
        if (threadIdx.x < off) sm[threadIdx.x] += sm[threadIdx.x + off];
        __syncthreads();
    }
    if (threadIdx.x == 0) bs[blockIdx.x] = sm[0];
}

__global__ __launch_bounds__(256) void scan_bs_k(int* __restrict__ bs, int nb) {
    __shared__ int sm[256];
    int t = threadIdx.x;
    int v = (t < nb) ? bs[t] : 0;
    sm[t] = v; __syncthreads();
    for (int off = 1; off < 256; off <<= 1) {
        int add = (t >= off) ? sm[t - off] : 0;
        __syncthreads();
        sm[t] += add;
        __syncthreads();
    }
    if (t < nb) bs[t] = sm[t] - v;   // exclusive
}

__global__ __launch_bounds__(256) void scan_write_k(const int* __restrict__ in,
                                                    const int* __restrict__ bs,
                                                    int* __restrict__ out, int n) {
    __shared__ int sm[256];
    int t = threadIdx.x;
    int base = blockIdx.x * 2048 + t * 8;
    int loc[8]; int s = 0;
    #pragma unroll
    for (int i = 0; i < 8; ++i) {
        int idx = base + i;
        loc[i] = (idx < n) ? in[idx] : 0;
        s += loc[i];
    }
    sm[t] = s; __syncthreads();
    int sv = s;
    for (int off = 1; off < 256; off <<= 1) {
        int add = (t >= off) ? sm[t - off] : 0;
        __syncthreads();
        sm[t] += add;
        __syncthreads();
    }
    int thOff = bs[blockIdx.x] + sm[t] - sv;
    int run = 0;
    #pragma unroll
    for (int i = 0; i < 8; ++i) {
        int idx = base + i;
        if (idx < n) out[idx] = thOff + run;
        run += loc[i];
    }
}

// scatter: one NT 8B write per direction; low word = BYTE offset of the
// partner's tmp row (idx * 1280), high word = edge value bits
__global__ __launch_bounds__(256) void scatter_k(
    const int* __restrict__ su, const int* __restrict__ si,
    const float* __restrict__ sv,
    int* __restrict__ posU, int* __restrict__ posV,
    unsigned long long* __restrict__ eU, unsigned long long* __restrict__ eV)
{
    int e = blockIdx.x * 256 + threadIdx.x;
    if (e >= NEDGE) return;
    int k = e / ESUP;
    int r = su[e], c = si[e];
    unsigned long long vb = (unsigned long long)(unsigned)__float_as_int(sv[e]) << 32;
    int pu = atomicAdd(&posU[k * NU + r], 1);
    __builtin_nontemporal_store(vb | (unsigned)(c * (TMPW * 2)), &eU[pu]);
    int pv = atomicAdd(&posV[k * NV + c], 1);
    __builtin_nontemporal_store(vb | (unsigned)(r * (TMPW * 2)), &eV[pv]);
}

// ---------------------------------------------------------------------------
// CSR aggregation, all supports (blockIdx.y = k), both directions.
// ONE wave per (node, k): lane l covers cols 2l,2l+1 via one u32 gather from
// the 256B-aligned k-slice of the partner's padded tmp row. NT packed stores
// into X[n][576] (cols k*100..k*100+99; k==4 lanes 50..55 zero cols 564..575).
__global__ __launch_bounds__(256) void agg_csr_k(
    const int* __restrict__ rowPtrU, const int2* __restrict__ eU,
    const int* __restrict__ rowPtrV, const int2* __restrict__ eV,
    const ushort* __restrict__ tmpU, const ushort* __restrict__ tmpV,
    ushort* __restrict__ Xu, ushort* __restrict__ Xv)
{
    const int k = blockIdx.y;
    const int lane = threadIdx.x & 63;
    const int wv = blockIdx.x * 4 + (threadIdx.x >> 6);   // global wave id
    const uint lo4 = (uint)(((lane < 50) ? lane : 49) << 2) + (uint)(k << 8);

    if (wv < NU) {
        // U direction: avg degree 4, batch 4; gathers tmpV rows
        const int n = wv;
        const int g = k * NU + n;
        const int s = rowPtrU[g];
        const int e = (g == KSUP * NU - 1) ? NEDGE : rowPtrU[g + 1];
        const int d = e - s;
        const char* tV = (const char*)tmpV;
        float a0 = 0.f, a1 = 0.f;
        for (int base = 0; base < d; base += 4) {
            int2 ed[4];
            #pragma unroll
            for (int i = 0; i < 4; ++i) {
                int idx = base + i; if (idx >= d) idx = base;
                ed[i] = eU[s + idx];
            }
            uint gw[4];
            #pragma unroll
            for (int i = 0; i < 4; ++i)
                gw[i] = *(const uint*)(tV + ((uint)ed[i].x + lo4));
            #pragma unroll
            for (int i = 0; i < 4; ++i) {
                if (base + i < d) {
                    float v = __int_as_float(ed[i].y);
                    a0 = fmaf(v, lof(gw[i]), a0);
                    a1 = fmaf(v, hif(gw[i]), a1);
                }
            }
        }
        uint payload = (uint)f2bf(fmaxf(a0, 0.f)) | ((uint)f2bf(fmaxf(a1, 0.f)) << 16);
        if (lane < 50)
            __builtin_nontemporal_store(payload,
                (uint*)(Xu + (size_t)n * XW + k * FSUP) + lane);
        else if (k == 4 && lane < 56)
            __builtin_nontemporal_store(0u,
                (uint*)(Xu + (size_t)n * XW + 564) + (lane - 50));
    } else {
        // V direction: avg degree 8, batch 8; gathers tmpU rows
        const int n = wv - NU;
        const int g = k * NV + n;
        const int s = rowPtrV[g];
        const int e = (g == KSUP * NV - 1) ? NEDGE : rowPtrV[g + 1];
        const int d = e - s;
        const char* tU = (const char*)tmpU;
        float a0 = 0.f, a1 = 0.f;
        for (int base = 0; base < d; base += 8) {
            int2 ed[8];
            #pragma unroll
            for (int i = 0; i < 8; ++i) {
                int idx = base + i; if (idx >= d) idx = base;
                ed[i] = eV[s + idx];
            }
            uint gw[8];
            #pragma unroll
            for (int i = 0; i < 8; ++i)
                gw[i] = *(const uint*)(tU + ((uint)ed[i].x + lo4));
            #pragma unroll
            for (int i = 0; i < 8; ++i) {
                if (base + i < d) {
                    float v = __int_as_float(ed[i].y);
                    a0 = fmaf(v, lof(gw[i]), a0);
                    a1 = fmaf(v, hif(gw[i]), a1);
                }
            }
        }
        uint payload = (uint)f2bf(fmaxf(a0, 0.f)) | ((uint)f2bf(fmaxf(a1, 0.f)) << 16);
        if (lane < 50)
            __builtin_nontemporal_store(payload,
                (uint*)(Xv + (size_t)n * XW + k * FSUP) + lane);
        else if (k == 4 && lane < 56)
            __builtin_nontemporal_store(0u,
                (uint*)(Xv + (size_t)n * XW + 564) + (lane - 50));
    }
}

// ---------------------------------------------------------------------------
// final decoder: basis[b] = dot(embU[u], Vb[v][b]); out = basis @ cls
__global__ __launch_bounds__(256) void dec_k(
    const int* __restrict__ ue, const int* __restrict__ ie,
    const ushort* __restrict__ embU, const ushort* __restrict__ Vb,
    const float* __restrict__ cls, float* __restrict__ out, int nE)
{
    int e = blockIdx.x * 8 + (threadIdx.x >> 5);
    if (e >= nE) return;
    int lane = threadIdx.x & 31;
    int u = ue[e], v = ie[e];
    const uint* pu = (const uint*)(embU + (size_t)u * DENC);        // 64 u32
    const uint* pv = (const uint*)(Vb + (size_t)v * (NBAS * DENC)); // 192 u32
    uint u0 = pu[lane], u1 = pu[lane + 32];
    uint b0[NBAS], b1[NBAS];
    #pragma unroll
    for (int b = 0; b < NBAS; ++b) {
        b0[b] = pv[b * 64 + lane];
        b1[b] = pv[b * 64 + 32 + lane];
    }
    float u0l = lof(u0), u0h = hif(u0), u1l = lof(u1), u1h = hif(u1);
    float s[NBAS];
    #pragma unroll
    for (int b = 0; b < NBAS; ++b) {
        float t = lof(b0[b]) * u0l;
        t = fmaf(hif(b0[b]), u0h, t);
        t = fmaf(lof(b1[b]), u1l, t);
        s[b] = fmaf(hif(b1[b]), u1h, t);
    }
    #pragma unroll
    for (int off = 16; off; off >>= 1)
        #pragma unroll
        for (int b = 0; b < NBAS; ++b) s[b] += __shfl_xor(s[b], off, 32);
    if (lane < NCLS) {
        float o = 0.f;
        #pragma unroll
        for (int b = 0; b < NBAS; ++b) o += s[b] * cls[b * NCLS + lane];
        out[(size_t)e * NCLS + lane] = o;
    }
}

// ---------------------------------------------------------------------------
extern "C" void kernel_launch(void* const* d_in, const int* in_sizes, int n_in,
                              void* d_out, int out_size, void* d_ws, size_t ws_size,
                              hipStream_t stream) {
    const int*   sup_u  = (const int*)  d_in[0];
    const int*   sup_i  = (const int*)  d_in[1];
    const float* sup_v  = (const float*)d_in[2];
    const float* u_in   = (const float*)d_in[3];
    const float* v_in   = (const float*)d_in[4];
    const float* u_side = (const float*)d_in[5];
    const float* v_side = (const float*)d_in[6];
    const int*   ue     = (const int*)  d_in[7];
    const int*   ie     = (const int*)  d_in[8];
    const float* W_enc  = (const float*)d_in[9];
    const float* Wu1    = (const float*)d_in[10];
    const float* bu1    = (const float*)d_in[11];
    const float* Wi1    = (const float*)d_in[12];
    const float* bi1    = (const float*)d_in[13];
    const float* Wu2    = (const float*)d_in[14];
    const float* Wi2    = (const float*)d_in[15];
    const float* dec_W  = (const float*)d_in[16];
    const float* deccls = (const float*)d_in[17];

    char* ws = (char*)d_ws;
    // timeline-overlaid workspace (max ~414M):
    // @0: u_bf [NU][512] (102.4M) -> Xu [NU][576] (115.2M)
    // @102.4M: v_bf [NV][512] (51.2M); Xv @115.2M [NV][576] (57.6M) ends 172.8M
    ushort* u_bf   = (ushort*)(ws);
    ushort* v_bf   = (ushort*)(ws + 102400000LL);
    ushort* Xu     = (ushort*)(ws);
    ushort* Xv     = (ushort*)(ws + 115200000LL);
    // CSR @176M (dead after agg):
    int*    histU  = (int*)(ws + 176000000LL);          // [5][NU] 2M
    int*    histV  = (int*)(ws + 178000000LL);          // [5][NV] 1M
    int*    rowPtrU= (int*)(ws + 179000000LL);          // 2M
    int*    rowPtrV= (int*)(ws + 181000000LL);          // 1M
    int*    posU   = (int*)(ws + 182000000LL);          // 2M
    int*    posV   = (int*)(ws + 184000000LL);          // 1M
    int*    bsums  = (int*)(ws + 185000000LL);          // 4KB
    unsigned long long* eU = (unsigned long long*)(ws + 186000000LL);  // 16M
    unsigned long long* eV = (unsigned long long*)(ws + 202000000LL);  // 16M ends 218M
    // tmp @220M (dead after agg): tmpU [NU][640] 128M, tmpV [NV][640] 64M
    ushort* tmpU   = (ushort*)(ws + 220000000LL);
    ushort* tmpV   = (ushort*)(ws + 348000000LL);       // ends 412M
    // post-agg overlays:
    ushort* embUbf = (ushort*)(ws + 176000000LL);       // [NU][128] 25.6M (over CSR)
    ushort* embVbf = (ushort*)(ws + 202000000LL);       // [NV][128] 12.8M (over eV)
    ushort* Vb     = (ushort*)(ws + 220000000LL);       // [NV][384] 38.4M (over tmp)
    // weights @412M:
    ushort* WencT2 = (ushort*)(ws + 412000000LL);       // [640][512] 0.66M
    ushort* W2ufT  = (ushort*)(ws + 413000000LL);       // [128][576] 0.15M
    ushort* W2ifT  = (ushort*)(ws + 413200000LL);       // [128][576] 0.15M
    ushort* decbf  = (ushort*)(ws + 413400000LL);       // [384][128] 0.10M

    dim3 blk(256);
    const int gu128 = (NU + 127) / 128;   // 782
    const int gv128 = (NV + 127) / 128;   // 391
    const int gu64  = (NU + 63) / 64;     // 1563
    const int gv64  = (NV + 63) / 64;     // 782
    const int gE    = (NEDGE + 255) / 256;

    // ---- phase 1: bf16 conversions + CSR build ----
    cvt_k<<<dim3((NU * 512 / 4 + 255) / 256), blk, 0, stream>>>(u_in, u_bf, (long)NU * 512);
    cvt_k<<<dim3((NV * 512 / 4 + 255) / 256), blk, 0, stream>>>(v_in, v_bf, (long)NV * 512);
    cvt_wencT2_k<<<dim3(TMPW * 512 / 256), blk, 0, stream>>>(W_enc, WencT2);
    cvt_w2fT_k<<<dim3((DENC * XW + 255) / 256), blk, 0, stream>>>(Wu2, W2ufT);
    cvt_w2fT_k<<<dim3((DENC * XW + 255) / 256), blk, 0, stream>>>(Wi2, W2ifT);
    cvt_k<<<dim3((NBAS * DENC * DENC / 4 + 255) / 256), blk, 0, stream>>>(
        dec_W, decbf, (long)NBAS * DENC * DENC);

    hipMemsetAsync(histU, 0, 3000000LL, stream);   // histU + histV contiguous
    hist_k<<<dim3(gE), blk, 0, stream>>>(sup_u, sup_i, histU, histV);
    scan_reduce_k<<<dim3(245), blk, 0, stream>>>(histU, bsums, KSUP * NU);
    scan_bs_k<<<dim3(1), blk, 0, stream>>>(bsums, 245);
    scan_write_k<<<dim3(245), blk, 0, stream>>>(histU, bsums, rowPtrU, KSUP * NU);
    scan_reduce_k<<<dim3(123), blk, 0, stream>>>(histV, bsums, KSUP * NV);
    scan_bs_k<<<dim3(1), blk, 0, stream>>>(bsums, 123);
    scan_write_k<<<dim3(123), blk, 0, stream>>>(histV, bsums, rowPtrV, KSUP * NV);
    hipMemcpyAsync(posU, rowPtrU, (size_t)KSUP * NU * 4, hipMemcpyDeviceToDevice, stream);
    hipMemcpyAsync(posV, rowPtrV, (size_t)KSUP * NV * 4, hipMemcpyDeviceToDevice, stream);
    scatter_k<<<dim3(gE), blk, 0, stream>>>(sup_u, sup_i, sup_v, posU, posV, eU, eV);

    // ---- phase 2: encoder GEMMs into padded tmp (N=640, 256B slices) ----
    gemm_bf16_k<1><<<dim3(gu128, TMPW / 128), blk, 0, stream>>>(
        u_bf, WencT2, tmpU, NU, TMPW, 512, TMPW);
    gemm_bf16_k<1><<<dim3(gv128, TMPW / 128), blk, 0, stream>>>(
        v_bf, WencT2, tmpV, NV, TMPW, 512, TMPW);

    // ---- phase 3: CSR aggregation (1 wave/node/support) -> X cols 0..499 ----
    agg_csr_k<<<dim3((NU + NV) / 4, KSUP), blk, 0, stream>>>(
        rowPtrU, (const int2*)eU, rowPtrV, (const int2*)eV, tmpU, tmpV, Xu, Xv);

    // ---- phase 4: side dense -> X cols 500..563 (bf16) ----
    gemm_side_k<<<dim3(gu64), blk, 0, stream>>>(u_side, Wu1, bu1, Xu, NU, DSIDE);
    gemm_side_k<<<dim3(gv64), blk, 0, stream>>>(v_side, Wi1, bi1, Xv, NV, DSIDE);

    // ---- phase 5: dense2 = X @ W2fT (K=576) -> emb bf16 ----
    gemm_bf16_k<1><<<dim3(gu128, 1), blk, 0, stream>>>(Xu, W2ufT, embUbf, NU, 128, XW, 128);
    gemm_bf16_k<1><<<dim3(gv128, 1), blk, 0, stream>>>(Xv, W2ifT, embVbf, NV, 128, XW, 128);

    // ---- phase 6: decoder precompute on V side: Vb = embV @ dec_W^T-free ----
    gemm_bf16_k<1><<<dim3(gv128, 3), blk, 0, stream>>>(embVbf, decbf, Vb, NV, 384, 128, 384);

    // ---- phase 7: final decoder over edges ----
    dec_k<<<dim3(NE / 8), blk, 0, stream>>>(ue, ie, embUbf, Vb, deccls, (float*)d_out, NE);
}

// Round 9
// 1323.157 us; speedup vs baseline: 1.7187x; 1.0608x over previous
//
#include <hip/hip_runtime.h>

// Problem constants (fixed by the reference)
#define NU 100000
#define NV 50000
#define KSUP 5
#define ESUP 400000
#define NEDGE (KSUP * ESUP)   // 2,000,000
#define NE 500000
#define DIN 512
#define DGCN 500
#define FSUP 100     // DGCN / KSUP
#define DSIDE 128
#define HSIDE 64
#define DENC 128
#define NBAS 3
#define NCLS 5

#define TMPW 640     // padded tmp width: 5 supports x 128 (256B-aligned slices)
#define XW 576       // X width: 500 gcn + 64 side + 12 pad (K = 9*64)

__device__ __forceinline__ ushort f2bf(float x) {
    union { float f; unsigned u; } c; c.f = x;
    unsigned r = (c.u + 0x7FFFu + ((c.u >> 16) & 1u)) >> 16;   // RNE
    return (ushort)r;
}
__device__ __forceinline__ float bf2f(ushort h) {
    union { unsigned u; float f; } c; c.u = ((unsigned)h) << 16;
    return c.f;
}
// unpack a u32 holding two bf16 (lo = even col, hi = odd col)
__device__ __forceinline__ float lof(uint g) { return __uint_as_float(g << 16); }
__device__ __forceinline__ float hif(uint g) { return __uint_as_float(g & 0xffff0000u); }

typedef __attribute__((ext_vector_type(4))) float f32x4;
typedef __attribute__((ext_vector_type(8))) short bf16x8;
typedef __attribute__((address_space(3))) void lds_void;
typedef const __attribute__((address_space(1))) void glob_void;

// ---------------------------------------------------------------------------
// bf16 MFMA GEMM: C[M,N] = A[M,K](bf16,K-major) @ BT[N,K](bf16,K-major)^T
// 128x128 tile, BK=64, 4 waves (2x2). LDS XOR-swizzled via pre-swizzled
// global source (rule #21). STORE_BF16: 1 -> C ushort, 0 -> C float.
template<int STORE_BF16>
__global__ __launch_bounds__(256) void gemm_bf16_k(
    const ushort* __restrict__ A, const ushort* __restrict__ BT,
    void* __restrict__ Cout, int M, int N, int K, int ldc)
{
    __shared__ ushort As[128 * 64];
    __shared__ ushort Bs[128 * 64];
    const int t = threadIdx.x;
    const int lane = t & 63;
    const int w = t >> 6;
    const int wr = w >> 1, wc = w & 1;
    const int rowBase = blockIdx.x * 128;
    const int colBase = blockIdx.y * 128;

    f32x4 acc[4][4] = {};

    for (int k0 = 0; k0 < K; k0 += 64) {
        #pragma unroll
        for (int i = 0; i < 4; ++i) {
            int chi = i * 256 + t;
            int r = chi >> 3;
            int c = (((chi >> 3) & 7) ^ (chi & 7)) * 8;
            int ga = rowBase + r; if (ga > M - 1) ga = M - 1;
            __builtin_amdgcn_global_load_lds(
                (glob_void*)(A + (size_t)ga * K + k0 + c),
                (lds_void*)(As + (size_t)chi * 8), 16, 0, 0);
            int gb = colBase + r; if (gb > N - 1) gb = N - 1;
            __builtin_amdgcn_global_load_lds(
                (glob_void*)(BT + (size_t)gb * K + k0 + c),
                (lds_void*)(Bs + (size_t)chi * 8), 16, 0, 0);
        }
        __syncthreads();

        #pragma unroll
        for (int kk = 0; kk < 2; ++kk) {
            bf16x8 af[4], bfr[4];
            const int cb2 = (kk * 32 + (lane >> 4) * 8) * 2;
            #pragma unroll
            for (int mi = 0; mi < 4; ++mi) {
                int r = wr * 64 + mi * 16 + (lane & 15);
                int off = (r * 128 + cb2) ^ ((r & 7) << 4);
                af[mi] = *(const bf16x8*)((const char*)As + off);
            }
            #pragma unroll
            for (int nj = 0; nj < 4; ++nj) {
                int r = wc * 64 + nj * 16 + (lane & 15);
                int off = (r * 128 + cb2) ^ ((r & 7) << 4);
                bfr[nj] = *(const bf16x8*)((const char*)Bs + off);
            }
            #pragma unroll
            for (int mi = 0; mi < 4; ++mi)
                #pragma unroll
                for (int nj = 0; nj < 4; ++nj)
                    acc[mi][nj] = __builtin_amdgcn_mfma_f32_16x16x32_bf16(
                        af[mi], bfr[nj], acc[mi][nj], 0, 0, 0);
        }
        __syncthreads();
    }

    #pragma unroll
    for (int mi = 0; mi < 4; ++mi) {
        #pragma unroll
        for (int q = 0; q < 4; ++q) {
            int gr = rowBase + wr * 64 + mi * 16 + (lane >> 4) * 4 + q;
            if (gr >= M) continue;
            #pragma unroll
            for (int nj = 0; nj < 4; ++nj) {
                int gc = colBase + wc * 64 + nj * 16 + (lane & 15);
                float v = acc[mi][nj][q];
                if (STORE_BF16)
                    ((ushort*)Cout)[(size_t)gr * ldc + gc] = f2bf(v);
                else
                    ((float*)Cout)[(size_t)gr * ldc + gc] = v;
            }
        }
    }
}

// ---------------------------------------------------------------------------
// side dense (fp32 compute): writes bf16 relu(A@B+bias) into X cols [500,564)
#define BM 64
#define BN 64
#define BK 16
__global__ __launch_bounds__(256) void gemm_side_k(
    const float* __restrict__ A, const float* __restrict__ B,
    const float* __restrict__ bias, ushort* __restrict__ X,
    int M, int K)
{
    __shared__ float As[BK][BM + 4];
    __shared__ float Bs[BK][BN + 4];
    const int t = threadIdx.x;
    const int rowBase = blockIdx.x * BM;
    const int ty = t >> 4, tx = t & 15;
    float acc[4][4] = {};

    for (int k0 = 0; k0 < K; k0 += BK) {
        #pragma unroll
        for (int p = 0; p < 4; ++p) {
            int r = p * 16 + (t >> 4), kk = t & 15;
            int gr = rowBase + r, gk = k0 + kk;
            As[kk][r] = (gr < M && gk < K) ? A[(size_t)gr * K + gk] : 0.f;
        }
        #pragma unroll
        for (int p = 0; p < 4; ++p) {
            int kk = p * 4 + (t >> 6), j = t & 63;
            int gk = k0 + kk;
            Bs[kk][j] = (j < HSIDE && gk < K) ? B[(size_t)gk * HSIDE + j] : 0.f;
        }
        __syncthreads();
        #pragma unroll
        for (int kk = 0; kk < BK; ++kk) {
            float4 a4 = *reinterpret_cast<const float4*>(&As[kk][ty * 4]);
            float4 b4 = *reinterpret_cast<const float4*>(&Bs[kk][tx * 4]);
            float aa[4] = {a4.x, a4.y, a4.z, a4.w};
            float bb[4] = {b4.x, b4.y, b4.z, b4.w};
            #pragma unroll
            for (int i = 0; i < 4; ++i)
                #pragma unroll
                for (int j = 0; j < 4; ++j)
                    acc[i][j] = fmaf(aa[i], bb[j], acc[i][j]);
        }
        __syncthreads();
    }
    #pragma unroll
    for (int i = 0; i < 4; ++i) {
        int gr = rowBase + ty * 4 + i;
        if (gr >= M) continue;
        #pragma unroll
        for (int j = 0; j < 4; ++j) {
            int gc = tx * 4 + j;
            if (gc < HSIDE)
                X[(size_t)gr * XW + 500 + gc] = f2bf(fmaxf(acc[i][j] + bias[gc], 0.f));
        }
    }
}

// ---------------------------------------------------------------------------
// conversions
__global__ __launch_bounds__(256) void cvt_k(const float* __restrict__ in,
                                             ushort* __restrict__ out, long n) {
    long i = ((long)blockIdx.x * 256 + threadIdx.x) * 4;
    if (i >= n) return;
    float4 v = *(const float4*)(in + i);
    ushort4 o;
    o.x = f2bf(v.x); o.y = f2bf(v.y); o.z = f2bf(v.z); o.w = f2bf(v.w);
    *(ushort4*)(out + i) = o;
}

// fused u/v input conversion
__global__ __launch_bounds__(256) void cvt_in_k(
    const float* __restrict__ u_in, const float* __restrict__ v_in,
    ushort* __restrict__ u_bf, ushort* __restrict__ v_bf)
{
    long i = ((long)blockIdx.x * 256 + threadIdx.x) * 4;
    const long nu = (long)NU * 512;
    const float* src; ushort* dst;
    if (i < nu) { src = u_in; dst = u_bf; }
    else {
        i -= nu;
        if (i >= (long)NV * 512) return;
        src = v_in; dst = v_bf;
    }
    float4 v = *(const float4*)(src + i);
    ushort4 o;
    o.x = f2bf(v.x); o.y = f2bf(v.y); o.z = f2bf(v.z); o.w = f2bf(v.w);
    *(ushort4*)(dst + i) = o;
}

// WencT2[n'][d], n' in [0,640): k=n'>>7, f=n'&127; val = f<100 ? W_enc[k][d][f] : 0
__global__ __launch_bounds__(256) void cvt_wencT2_k(const float* __restrict__ W,
                                                    ushort* __restrict__ out) {
    int idx = blockIdx.x * 256 + threadIdx.x;   // 640*512
    int np = idx >> 9, d = idx & 511;
    int k = np >> 7, f = np & 127;
    float v = (f < FSUP) ? W[((size_t)k * DIN + d) * FSUP + f] : 0.f;
    out[idx] = f2bf(v);
}

// W2fT[j][c] = bf16(W2[c][j]) for c<564, 0 for pad; both U and I via blockIdx.y
__global__ __launch_bounds__(256) void cvt_w2fT2_k(
    const float* __restrict__ Wu2, const float* __restrict__ Wi2,
    ushort* __restrict__ outU, ushort* __restrict__ outI)
{
    int idx = blockIdx.x * 256 + threadIdx.x;   // 128*576
    if (idx >= DENC * XW) return;
    const float* W = blockIdx.y ? Wi2 : Wu2;
    ushort* out = blockIdx.y ? outI : outU;
    int j = idx / XW, c = idx - j * XW;
    float v = (c < DGCN + HSIDE) ? W[(size_t)c * DENC + j] : 0.f;
    out[idx] = f2bf(v);
}

// ---------------------------------------------------------------------------
// CSR build: histogram, 3-kernel exclusive scan (writes rowPtr + pos +
// sentinel; rowPtr buffers have dedicated +4B headroom), scatter (u64, NT)
__global__ __launch_bounds__(256) void hist_k(
    const int* __restrict__ su, const int* __restrict__ si,
    int* __restrict__ histU, int* __restrict__ histV)
{
    int e = blockIdx.x * 256 + threadIdx.x;
    if (e >= NEDGE) return;
    int k = e / ESUP;
    atomicAdd(&histU[k * NU + su[e]], 1);
    atomicAdd(&histV[k * NV + si[e]], 1);
}

__global__ __launch_bounds__(256) void scan_reduce_k(const int* __restrict__ in,
                                                     int* __restrict__ bs, int n) {
    __shared__ int sm[256];
    int base = blockIdx.x * 2048 + threadIdx.x * 8;
    int s = 0;
    #pragma unroll
    for (int i = 0; i < 8; ++i) { int idx = base + i; if (idx < n) s += in[idx]; }
    sm[threadIdx.x] = s; __syncthreads();
    for (int off = 128; off; off >>= 1) {
        if (threadIdx.x < off) sm[threadIdx.x] += sm[threadIdx.x + off];
        __syncthreads();
    }
    if (threadIdx.x == 0) bs[blockIdx.x] = sm[0];
}

__global__ __launch_bounds__(256) void scan_bs_k(int* __restrict__ bs, int nb) {
    __shared__ int sm[256];
    int t = threadIdx.x;
    int v = (t < nb) ? bs[t] : 0;
    sm[t] = v; __syncthreads();
    for (int off = 1; off < 256; off <<= 1) {
        int add = (t >= off) ? sm[t - off] : 0;
        __syncthreads();
        sm[t] += add;
        __syncthreads();
    }
    if (t < nb) bs[t] = sm[t] - v;   // exclusive
}

__global__ __launch_bounds__(256) void scan_write_k(const int* __restrict__ in,
                                                    const int* __restrict__ bs,
                                                    int* __restrict__ out,
                                                    int* __restrict__ pos, int n) {
    __shared__ int sm[256];
    int t = threadIdx.x;
    int base = blockIdx.x * 2048 + t * 8;
    int loc[8]; int s = 0;
    #pragma unroll
    for (int i = 0; i < 8; ++i) {
        int idx = base + i;
        loc[i] = (idx < n) ? in[idx] : 0;
        s += loc[i];
    }
    sm[t] = s; __syncthreads();
    int sv = s;
    for (int off = 1; off < 256; off <<= 1) {
        int add = (t >= off) ? sm[t - off] : 0;
        __syncthreads();
        sm[t] += add;
        __syncthreads();
    }
    int thOff = bs[blockIdx.x] + sm[t] - sv;
    int run = 0;
    #pragma unroll
    for (int i = 0; i < 8; ++i) {
        int idx = base + i;
        if (idx < n) { int v = thOff + run; out[idx] = v; pos[idx] = v; }
        run += loc[i];
    }
    if (blockIdx.x == 0 && t == 0) out[n] = NEDGE;   // sentinel (padded buffer)
}

// scatter: one NT 8B write per direction; low word = BYTE offset of the
// partner's tmp row (idx * 1280), high word = edge value bits
__global__ __launch_bounds__(256) void scatter_k(
    const int* __restrict__ su, const int* __restrict__ si,
    const float* __restrict__ sv,
    int* __restrict__ posU, int* __restrict__ posV,
    unsigned long long* __restrict__ eU, unsigned long long* __restrict__ eV)
{
    int e = blockIdx.x * 256 + threadIdx.x;
    if (e >= NEDGE) return;
    int k = e / ESUP;
    int r = su[e], c = si[e];
    unsigned long long vb = (unsigned long long)(unsigned)__float_as_int(sv[e]) << 32;
    int pu = atomicAdd(&posU[k * NU + r], 1);
    __builtin_nontemporal_store(vb | (unsigned)(c * (TMPW * 2)), &eU[pu]);
    int pv = atomicAdd(&posV[k * NV + c], 1);
    __builtin_nontemporal_store(vb | (unsigned)(r * (TMPW * 2)), &eV[pv]);
}

// ---------------------------------------------------------------------------
// Merged-support CSR aggregation: ONE wave per node, all supports [K0,K0+NK)
// in one interleaved latency chain (rowPtrs -> edges -> gathers -> fma).
// Round 0: batch B (clamped, branch-free). Round 1: batch B, wave-uniform
// guarded. Serial tail beyond 2B (rare). a0/a1 statically indexed.
template<int K0, int NK, int B, int NNODE>
__device__ __forceinline__ void agg_do(
    const int* __restrict__ rowPtr, const int2* __restrict__ eArr,
    const char* __restrict__ tSrc, int n, uint lane4,
    float* __restrict__ a0, float* __restrict__ a1)
{
    int s[NK], d[NK];
    #pragma unroll
    for (int kk = 0; kk < NK; ++kk) {
        int g = (K0 + kk) * NNODE + n;
        int ss = rowPtr[g];
        int ee = rowPtr[g + 1];     // sentinel covers the last segment
        s[kk] = ss; d[kk] = ee - ss;
    }
    int2 ed[NK][B]; uint gw[NK][B];
    #pragma unroll
    for (int kk = 0; kk < NK; ++kk)
        #pragma unroll
        for (int i = 0; i < B; ++i) {
            int idx = (i < d[kk]) ? i : 0;
            int2 t = eArr[s[kk] + idx];
            if (i >= d[kk]) t.x = 0;
            ed[kk][i] = t;
        }
    #pragma unroll
    for (int kk = 0; kk < NK; ++kk)
        #pragma unroll
        for (int i = 0; i < B; ++i)
            gw[kk][i] = *(const uint*)(tSrc + ((uint)ed[kk][i].x + lane4 + ((uint)(K0 + kk) << 8)));
    #pragma unroll
    for (int kk = 0; kk < NK; ++kk) {
        float x0 = 0.f, x1 = 0.f;
        #pragma unroll
        for (int i = 0; i < B; ++i)
            if (i < d[kk]) {
                float v = __int_as_float(ed[kk][i].y);
                x0 = fmaf(v, lof(gw[kk][i]), x0);
                x1 = fmaf(v, hif(gw[kk][i]), x1);
            }
        a0[K0 + kk] = x0; a1[K0 + kk] = x1;
    }
    #pragma unroll
    for (int kk = 0; kk < NK; ++kk) {
        if (d[kk] > B) {            // wave-uniform branch
            int2 e1[B]; uint g1[B];
            #pragma unroll
            for (int i = 0; i < B; ++i) {
                int idx = (B + i < d[kk]) ? B + i : B;
                int2 t = eArr[s[kk] + idx];
                if (B + i >= d[kk]) t.x = 0;
                e1[i] = t;
            }
            #pragma unroll
            for (int i = 0; i < B; ++i)
                g1[i] = *(const uint*)(tSrc + ((uint)e1[i].x + lane4 + ((uint)(K0 + kk) << 8)));
            #pragma unroll
            for (int i = 0; i < B; ++i)
                if (B + i < d[kk]) {
                    float v = __int_as_float(e1[i].y);
                    a0[K0 + kk] = fmaf(v, lof(g1[i]), a0[K0 + kk]);
                    a1[K0 + kk] = fmaf(v, hif(g1[i]), a1[K0 + kk]);
                }
            for (int p = 2 * B; p < d[kk]; ++p) {
                int2 t = eArr[s[kk] + p];
                uint g = *(const uint*)(tSrc + ((uint)t.x + lane4 + ((uint)(K0 + kk) << 8)));
                float v = __int_as_float(t.y);
                a0[K0 + kk] = fmaf(v, lof(g), a0[K0 + kk]);
                a1[K0 + kk] = fmaf(v, hif(g), a1[K0 + kk]);
            }
        }
    }
}

__global__ __launch_bounds__(256) void agg_csr_k(
    const int* __restrict__ rowPtrU, const int2* __restrict__ eU,
    const int* __restrict__ rowPtrV, const int2* __restrict__ eV,
    const ushort* __restrict__ tmpU, const ushort* __restrict__ tmpV,
    ushort* __restrict__ Xu, ushort* __restrict__ Xv)
{
    const int lane = threadIdx.x & 63;
    const int wv = blockIdx.x * 4 + (threadIdx.x >> 6);   // node id (U then V)
    const uint lane4 = (uint)(((lane < 50) ? lane : 49) << 2);

    float a0[KSUP], a1[KSUP];
    ushort* Xrow;
    if (wv < NU) {
        // U node: avg degree 4/support, batch 4, all 5 supports interleaved
        agg_do<0, KSUP, 4, NU>(rowPtrU, eU, (const char*)tmpV, wv, lane4, a0, a1);
        Xrow = Xu + (size_t)wv * XW;
    } else {
        // V node: avg degree 8/support, batch 8, supports in groups {0,1,2},{3,4}
        int n = wv - NU;
        agg_do<0, 3, 8, NV>(rowPtrV, eV, (const char*)tmpU, n, lane4, a0, a1);
        agg_do<3, 2, 8, NV>(rowPtrV, eV, (const char*)tmpU, n, lane4, a0, a1);
        Xrow = Xv + (size_t)n * XW;
    }
    #pragma unroll
    for (int k = 0; k < KSUP; ++k) {
        uint payload = (uint)f2bf(fmaxf(a0[k], 0.f)) |
                       ((uint)f2bf(fmaxf(a1[k], 0.f)) << 16);
        if (lane < 50)
            __builtin_nontemporal_store(payload, (uint*)(Xrow + k * FSUP) + lane);
    }
    if (lane < 6)
        __builtin_nontemporal_store(0u, (uint*)(Xrow + 564) + lane);
}

// ---------------------------------------------------------------------------
// final decoder: basis[b] = dot(embU[u], Vb[v][b]); out = basis @ cls
__global__ __launch_bounds__(256) void dec_k(
    const int* __restrict__ ue, const int* __restrict__ ie,
    const ushort* __restrict__ embU, const ushort* __restrict__ Vb,
    const float* __restrict__ cls, float* __restrict__ out, int nE)
{
    int e = blockIdx.x * 8 + (threadIdx.x >> 5);
    if (e >= nE) return;
    int lane = threadIdx.x & 31;
    int u = ue[e], v = ie[e];
    const uint* pu = (const uint*)(embU + (size_t)u * DENC);        // 64 u32
    const uint* pv = (const uint*)(Vb + (size_t)v * (NBAS * DENC)); // 192 u32
    uint u0 = pu[lane], u1 = pu[lane + 32];
    uint b0[NBAS], b1[NBAS];
    #pragma unroll
    for (int b = 0; b < NBAS; ++b) {
        b0[b] = pv[b * 64 + lane];
        b1[b] = pv[b * 64 + 32 + lane];
    }
    float u0l = lof(u0), u0h = hif(u0), u1l = lof(u1), u1h = hif(u1);
    float s[NBAS];
    #pragma unroll
    for (int b = 0; b < NBAS; ++b) {
        float t = lof(b0[b]) * u0l;
        t = fmaf(hif(b0[b]), u0h, t);
        t = fmaf(lof(b1[b]), u1l, t);
        s[b] = fmaf(hif(b1[b]), u1h, t);
    }
    #pragma unroll
    for (int off = 16; off; off >>= 1)
        #pragma unroll
        for (int b = 0; b < NBAS; ++b) s[b] += __shfl_xor(s[b], off, 32);
    if (lane < NCLS) {
        float o = 0.f;
        #pragma unroll
        for (int b = 0; b < NBAS; ++b) o += s[b] * cls[b * NCLS + lane];
        out[(size_t)e * NCLS + lane] = o;
    }
}

// ---------------------------------------------------------------------------
extern "C" void kernel_launch(void* const* d_in, const int* in_sizes, int n_in,
                              void* d_out, int out_size, void* d_ws, size_t ws_size,
                              hipStream_t stream) {
    const int*   sup_u  = (const int*)  d_in[0];
    const int*   sup_i  = (const int*)  d_in[1];
    const float* sup_v  = (const float*)d_in[2];
    const float* u_in   = (const float*)d_in[3];
    const float* v_in   = (const float*)d_in[4];
    const float* u_side = (const float*)d_in[5];
    const float* v_side = (const float*)d_in[6];
    const int*   ue     = (const int*)  d_in[7];
    const int*   ie     = (const int*)  d_in[8];
    const float* W_enc  = (const float*)d_in[9];
    const float* Wu1    = (const float*)d_in[10];
    const float* bu1    = (const float*)d_in[11];
    const float* Wi1    = (const float*)d_in[12];
    const float* bi1    = (const float*)d_in[13];
    const float* Wu2    = (const float*)d_in[14];
    const float* Wi2    = (const float*)d_in[15];
    const float* dec_W  = (const float*)d_in[16];
    const float* deccls = (const float*)d_in[17];

    char* ws = (char*)d_ws;
    // timeline-overlaid workspace (max ~414M):
    // @0: u_bf [NU][512] (102.4M) -> Xu [NU][576] (115.2M)
    // @102.4M: v_bf [NV][512] (51.2M); Xv @115.2M [NV][576] (57.6M) ends 172.8M
    ushort* u_bf   = (ushort*)(ws);
    ushort* v_bf   = (ushort*)(ws + 102400000LL);
    ushort* Xu     = (ushort*)(ws);
    ushort* Xv     = (ushort*)(ws + 115200000LL);
    // CSR @176M (dead after agg). Each rowPtr has its own padded region so the
    // +1 sentinel cannot clobber the next buffer (R8 bug: V sentinel hit posU).
    int*    histU  = (int*)(ws + 176000000LL);          // [5][NU] 2M
    int*    histV  = (int*)(ws + 178000000LL);          // [5][NV] 1M
    int*    rowPtrU= (int*)(ws + 179000000LL);          // 2M + 4 sentinel
    int*    rowPtrV= (int*)(ws + 181200000LL);          // 1M + 4 sentinel
    int*    posU   = (int*)(ws + 182400000LL);          // 2M
    int*    posV   = (int*)(ws + 184600000LL);          // 1M
    int*    bsums  = (int*)(ws + 185800000LL);          // 4KB
    unsigned long long* eU = (unsigned long long*)(ws + 186000000LL);  // 16M
    unsigned long long* eV = (unsigned long long*)(ws + 202000000LL);  // 16M ends 218M
    // tmp @220M (dead after agg): tmpU [NU][640] 128M, tmpV [NV][640] 64M
    ushort* tmpU   = (ushort*)(ws + 220000000LL);
    ushort* tmpV   = (ushort*)(ws + 348000000LL);       // ends 412M
    // post-agg overlays:
    ushort* embUbf = (ushort*)(ws + 176000000LL);       // [NU][128] 25.6M (over CSR)
    ushort* embVbf = (ushort*)(ws + 202000000LL);       // [NV][128] 12.8M (over eV)
    ushort* Vb     = (ushort*)(ws + 220000000LL);       // [NV][384] 38.4M (over tmp)
    // weights @412M:
    ushort* WencT2 = (ushort*)(ws + 412000000LL);       // [640][512] 0.66M
    ushort* W2ufT  = (ushort*)(ws + 413000000LL);       // [128][576] 0.15M
    ushort* W2ifT  = (ushort*)(ws + 413200000LL);       // [128][576] 0.15M
    ushort* decbf  = (ushort*)(ws + 413400000LL);       // [384][128] 0.10M

    dim3 blk(256);
    const int gu128 = (NU + 127) / 128;   // 782
    const int gv128 = (NV + 127) / 128;   // 391
    const int gu64  = (NU + 63) / 64;     // 1563
    const int gv64  = (NV + 63) / 64;     // 782
    const int gE    = (NEDGE + 255) / 256;

    // ---- phase 1: bf16 conversions + CSR build ----
    cvt_in_k<<<dim3((NU + NV) * 512 / 4 / 256), blk, 0, stream>>>(u_in, v_in, u_bf, v_bf);
    cvt_wencT2_k<<<dim3(TMPW * 512 / 256), blk, 0, stream>>>(W_enc, WencT2);
    cvt_w2fT2_k<<<dim3((DENC * XW + 255) / 256, 2), blk, 0, stream>>>(Wu2, Wi2, W2ufT, W2ifT);
    cvt_k<<<dim3((NBAS * DENC * DENC / 4 + 255) / 256), blk, 0, stream>>>(
        dec_W, decbf, (long)NBAS * DENC * DENC);

    hipMemsetAsync(histU, 0, 3000000LL, stream);   // histU + histV contiguous
    hist_k<<<dim3(gE), blk, 0, stream>>>(sup_u, sup_i, histU, histV);
    scan_reduce_k<<<dim3(245), blk, 0, stream>>>(histU, bsums, KSUP * NU);
    scan_bs_k<<<dim3(1), blk, 0, stream>>>(bsums, 245);
    scan_write_k<<<dim3(245), blk, 0, stream>>>(histU, bsums, rowPtrU, posU, KSUP * NU);
    scan_reduce_k<<<dim3(123), blk, 0, stream>>>(histV, bsums, KSUP * NV);
    scan_bs_k<<<dim3(1), blk, 0, stream>>>(bsums, 123);
    scan_write_k<<<dim3(123), blk, 0, stream>>>(histV, bsums, rowPtrV, posV, KSUP * NV);
    scatter_k<<<dim3(gE), blk, 0, stream>>>(sup_u, sup_i, sup_v, posU, posV, eU, eV);

    // ---- phase 2: encoder GEMMs into padded tmp (N=640, 256B slices) ----
    gemm_bf16_k<1><<<dim3(gu128, TMPW / 128), blk, 0, stream>>>(
        u_bf, WencT2, tmpU, NU, TMPW, 512, TMPW);
    gemm_bf16_k<1><<<dim3(gv128, TMPW / 128), blk, 0, stream>>>(
        v_bf, WencT2, tmpV, NV, TMPW, 512, TMPW);

    // ---- phase 3: merged CSR aggregation (1 wave/node, 5 supports) ----
    agg_csr_k<<<dim3((NU + NV) / 4), blk, 0, stream>>>(
        rowPtrU, (const int2*)eU, rowPtrV, (const int2*)eV, tmpU, tmpV, Xu, Xv);

    // ---- phase 4: side dense -> X cols 500..563 (bf16) ----
    gemm_side_k<<<dim3(gu64), blk, 0, stream>>>(u_side, Wu1, bu1, Xu, NU, DSIDE);
    gemm_side_k<<<dim3(gv64), blk, 0, stream>>>(v_side, Wi1, bi1, Xv, NV, DSIDE);

    // ---- phase 5: dense2 = X @ W2fT (K=576) -> emb bf16 ----
    gemm_bf16_k<1><<<dim3(gu128, 1), blk, 0, stream>>>(Xu, W2ufT, embUbf, NU, 128, XW, 128);
    gemm_bf16_k<1><<<dim3(gv128, 1), blk, 0, stream>>>(Xv, W2ifT, embVbf, NV, 128, XW, 128);

    // ---- phase 6: decoder precompute on V side: Vb = embV @ decbf^T ----
    gemm_bf16_k<1><<<dim3(gv128, 3), blk, 0, stream>>>(embVbf, decbf, Vb, NV, 384, 128, 384);

    // ---- phase 7: final decoder over edges ----
    dec_k<<<dim3(NE / 8), blk, 0, stream>>>(ue, ie, embUbf, Vb, deccls, (float*)d_out, NE);
}